// Round 15
// baseline (112.444 us; speedup 1.0000x reference)
//
#include <hip/hip_runtime.h>

#define BATCH 8
#define CIN 128
#define OCH 128
#define T_LEN 16384
#define NS 256
#define CHUNK 64
#define NCHUNK (T_LEN / CHUNK)   // 256
#define THALF (T_LEN / 2)        // 8192
#define SCHUNK 8192              // u32 per chunk image in global: 32 rows x 256 n
#define HROW 132                 // Hr row stride (u32)
#define NCHK 4                   // chunks per apply block -> grid 512 = 2 blocks/CU

typedef __attribute__((ext_vector_type(8))) short bf16x8;
typedef __attribute__((ext_vector_type(4))) float f32x4;
typedef __attribute__((ext_vector_type(4))) unsigned int u32x4;

__device__ __forceinline__ unsigned int pk2(float lo, float hi) {
  unsigned int d;
  asm("v_cvt_pk_bf16_f32 %0, %1, %2" : "=v"(d) : "v"(lo), "v"(hi));
  return d;
}
__device__ __forceinline__ unsigned short f2bf(float f) {
  unsigned int u = __float_as_uint(f);
  u += 0x7fffu + ((u >> 16) & 1u);
  return (unsigned short)(u >> 16);
}
__device__ __forceinline__ float softplusf_(float v) {
  return (v > 20.0f) ? v : log1pf(expf(v));
}
// barrier that does NOT drain vmcnt (keeps global prefetch in flight)
__device__ __forceinline__ void rawbar() {
  __builtin_amdgcn_sched_barrier(0);
  asm volatile("s_waitcnt lgkmcnt(0)" ::: "memory");
  __builtin_amdgcn_sched_barrier(0);
  __builtin_amdgcn_s_barrier();
  __builtin_amdgcn_sched_barrier(0);
}

// ---------------- prep: weights -> bf16, A_d, A_d^L, PWf[tp][n] = A_n^(2tp+1) ----------------
__global__ __launch_bounds__(256) void k_prep(
    const float* __restrict__ rl, const float* __restrict__ Bc,
    const float* __restrict__ Cm, const float* __restrict__ W,
    unsigned short* __restrict__ BdT, unsigned short* __restrict__ CT,
    unsigned short* __restrict__ Wb, float* __restrict__ Ad, float* __restrict__ rL,
    float* __restrict__ PWf)
{
  const int tid = blockIdx.x * 256 + threadIdx.x;
  if (tid < NS * CIN) {                       // BdT[n][c] = B_c[c][n] * (A_d-1)/lam
    const int n = tid >> 7, c = tid & 127;
    float lam = -softplusf_(rl[n]);
    float ad = expf(lam);
    float sc = (ad - 1.0f) / lam;
    BdT[tid] = f2bf(Bc[c * NS + n] * sc);
  } else if (tid < 2 * NS * CIN) {            // CT[o][n] = C[n][o]
    const int i = tid - NS * CIN;
    const int o = i >> 8, n = i & 255;
    CT[i] = f2bf(Cm[n * OCH + o]);
  } else if (tid < 3 * NS * CIN) {            // Wb[o][c2] = W[o][c2]
    const int i = tid - 2 * NS * CIN;
    Wb[i] = f2bf(W[i]);
  } else if (tid < 3 * NS * CIN + NS) {
    const int n = tid - 3 * NS * CIN;
    float lam = -softplusf_(rl[n]);
    Ad[n] = expf(lam);
    rL[n] = expf(lam * (float)CHUNK);
  } else if (tid < 3 * NS * CIN + NS + 32 * NS) {   // PWf[tp][n] = A_n^(2tp+1)
    const int i = tid - (3 * NS * CIN + NS);
    const int tp = i >> 8, n = i & 255;
    float lam = -softplusf_(rl[n]);
    PWf[i] = expf(lam * (float)(2 * tp + 1));
  }
}

// ---------------- chunk-carry combine: Hillis-Steele with multiplier A^L ----------------
__global__ __launch_bounds__(256) void k_combine(float* __restrict__ carry,
                                                 const float* __restrict__ rL)
{
  const int b = blockIdx.x >> 3;
  const int ng = blockIdx.x & 7;      // n-group of 32
  const int t = threadIdx.x;          // chunk index
  __shared__ float Y[32][NCHUNK];
  float* base = carry + ((size_t)b * NCHUNK + t) * NS + ng * 32;
  #pragma unroll
  for (int i4 = 0; i4 < 8; ++i4) {
    float4 q = *(const float4*)(base + i4 * 4);
    Y[i4 * 4 + 0][t] = q.x; Y[i4 * 4 + 1][t] = q.y;
    Y[i4 * 4 + 2][t] = q.z; Y[i4 * 4 + 3][t] = q.w;
  }
  float rp[32];
  #pragma unroll
  for (int i = 0; i < 32; ++i) rp[i] = rL[ng * 32 + i];
  __syncthreads();
  for (int d = 1; d < NCHUNK; d <<= 1) {
    float tmp[32];
    #pragma unroll
    for (int i = 0; i < 32; ++i) tmp[i] = (t >= d) ? Y[i][t - d] : 0.0f;
    __syncthreads();
    #pragma unroll
    for (int i = 0; i < 32; ++i) { Y[i][t] += rp[i] * tmp[i]; rp[i] *= rp[i]; }
    __syncthreads();
  }
  const int tm = (t == 0) ? 0 : (t - 1);
  #pragma unroll
  for (int i4 = 0; i4 < 8; ++i4) {
    float a = Y[i4 * 4 + 0][tm], bb = Y[i4 * 4 + 1][tm];
    float c = Y[i4 * 4 + 2][tm], dd = Y[i4 * 4 + 3][tm];
    float4 q;
    q.x = (t == 0) ? 0.0f : a;  q.y = (t == 0) ? 0.0f : bb;
    q.z = (t == 0) ? 0.0f : c;  q.w = (t == 0) ? 0.0f : dd;
    *(float4*)(base + i4 * 4) = q;
  }
}

// ---------------- k_scan: R13 exact version ((512,4), hoisted Bf) ----------------
__global__ __launch_bounds__(512, 4) void k_scan(
    const float* __restrict__ x,
    const unsigned short* __restrict__ BdT,
    const float* __restrict__ Ad,
    unsigned int* __restrict__ s0,
    float* __restrict__ carry)
{
  const int bid = blockIdx.x;
  const int b = bid >> 8;
  const int kc = bid & 255;
  const int tid = threadIdx.x;
  const int w = tid >> 6, l = tid & 63, l15 = l & 15, g = l >> 4;

  __shared__ __align__(16) unsigned int Xt[64 * 64];  // [t][c2 ^ ((t&7)<<2)] packed bf16 pairs

  {
    const int c2 = w * 8 + (l & 7);
    const int t0b = (l >> 3) * 8;
    const float* r0 = x + ((size_t)(b * CIN + 2 * c2)) * T_LEN + kc * CHUNK + t0b;
    const f32x4 xa0 = *(const f32x4*)r0;
    const f32x4 xa1 = *(const f32x4*)(r0 + 4);
    const f32x4 xb0 = *(const f32x4*)(r0 + T_LEN);
    const f32x4 xb1 = *(const f32x4*)(r0 + T_LEN + 4);
    #pragma unroll
    for (int k = 0; k < 8; ++k) {
      const int t = t0b + k;
      const float va = (k < 4) ? xa0[k & 3] : xa1[k & 3];
      const float vb = (k < 4) ? xb0[k & 3] : xb1[k & 3];
      Xt[t * 64 + (c2 ^ ((t & 7) << 2))] = pk2(va, vb);
    }
  }

  bf16x8 Bf[2][4];
  #pragma unroll
  for (int nt = 0; nt < 2; ++nt)
    #pragma unroll
    for (int kt = 0; kt < 4; ++kt)
      Bf[nt][kt] = *(const bf16x8*)&BdT[(w * 32 + nt * 16 + l15) * CIN + kt * 32 + g * 8];

  float A1[2], A2[2], A3[2], A4[2], A8[2], A16[2], A4G[2], M1[2], M2[2];
  #pragma unroll
  for (int nt = 0; nt < 2; ++nt) {
    const float a1 = Ad[w * 32 + nt * 16 + l15];
    A1[nt] = a1; A2[nt] = a1 * a1; A3[nt] = A2[nt] * a1; A4[nt] = A2[nt] * A2[nt];
    A8[nt] = A4[nt] * A4[nt]; A16[nt] = A8[nt] * A8[nt];
    float a4g = 1.0f;
    if (g & 1) a4g *= A4[nt];
    if (g & 2) a4g *= A8[nt];
    A4G[nt] = a4g;
    M1[nt] = (g >= 1) ? A4[nt] : 0.0f;
    M2[nt] = (g >= 2) ? A8[nt] : 0.0f;
  }
  __syncthreads();

  f32x4 vac[4][2] = {};
  #pragma unroll
  for (int kt = 0; kt < 4; ++kt) {
    bf16x8 afr[4];
    #pragma unroll
    for (int mt = 0; mt < 4; ++mt)
      afr[mt] = *(const bf16x8*)&Xt[(mt * 16 + l15) * 64 + ((kt * 16 + g * 4) ^ ((l15 & 7) << 2))];
    #pragma unroll
    for (int nt = 0; nt < 2; ++nt)
      #pragma unroll
      for (int mt = 0; mt < 4; ++mt)
        vac[mt][nt] = __builtin_amdgcn_mfma_f32_16x16x32_bf16(afr[mt], Bf[nt][kt], vac[mt][nt], 0, 0, 0);
  }

  float crv[2];
  #pragma unroll
  for (int nt = 0; nt < 2; ++nt) {
    float cr = 0.0f;
    #pragma unroll
    for (int mt = 0; mt < 4; ++mt) {
      const float p0 = vac[mt][nt][0];
      const float p1 = fmaf(A1[nt], p0, vac[mt][nt][1]);
      const float p2 = fmaf(A1[nt], p1, vac[mt][nt][2]);
      const float p3 = fmaf(A1[nt], p2, vac[mt][nt][3]);
      float c0 = p3;
      float u = __shfl_up(c0, 16);
      c0 = fmaf(M1[nt], u, c0);
      u = __shfl_up(c0, 32);
      c0 = fmaf(M2[nt], u, c0);
      float e = __shfl_up(c0, 16);
      e = (g == 0) ? 0.0f : e;
      const float seed = fmaf(A4G[nt], cr, e);
      vac[mt][nt][0] = fmaf(A1[nt], seed, p0);
      vac[mt][nt][1] = fmaf(A2[nt], seed, p1);
      vac[mt][nt][2] = fmaf(A3[nt], seed, p2);
      vac[mt][nt][3] = fmaf(A4[nt], seed, p3);
      const float ctop = __shfl(c0, 48 + l15);
      cr = fmaf(A16[nt], cr, ctop);
    }
    crv[nt] = cr;
  }

  unsigned int* sc = s0 + (size_t)(b * NCHUNK + kc) * SCHUNK;
  #pragma unroll
  for (int mt = 0; mt < 4; ++mt)
    #pragma unroll
    for (int nt = 0; nt < 2; ++nt) {
      const int n = w * 32 + nt * 16 + l15;
      #pragma unroll
      for (int rp = 0; rp < 2; ++rp) {
        const int tp = mt * 8 + g * 2 + rp;
        sc[tp * 256 + n] = pk2(vac[mt][nt][rp * 2], vac[mt][nt][rp * 2 + 1]);
      }
    }
  if (g == 0) {
    #pragma unroll
    for (int nt = 0; nt < 2; ++nt)
      carry[((size_t)b * NCHUNK + kc) * NS + (w * 32 + nt * 16 + l15)] = crv[nt];
  }
}

// ---------------- k_apply: 256-thread blocks (4 waves), 2 INDEPENDENT blocks/CU ----------------
// R15: R13's single block/CU convoyed at barriers (~66% idle, 31K cy/iter vs ~5K work).
// 4-wave blocks at 51.7 KB LDS -> 2 blocks/CU with independent barriers; when one block
// stalls the other fills the CU. (256,2) -> 2 waves/SIMD, ~256-VGPR cap (no spill).
// Wave w = o-quarter; each wave covers all 64 t of its chunk.
__global__ __launch_bounds__(256, 2) void k_apply(
    const unsigned int* __restrict__ S,
    const unsigned short* __restrict__ CT,
    const unsigned short* __restrict__ Wb,
    const float* __restrict__ PWf,
    const float* __restrict__ Ad,
    const float* __restrict__ carry,
    const float* __restrict__ lng, const float* __restrict__ lnb,
    const float* __restrict__ bias,
    float* __restrict__ out)
{
  const int bid = blockIdx.x;
  const int b = bid / (NCHUNK / NCHK);
  const int kc0 = (bid % (NCHUNK / NCHK)) * NCHK;
  const int tid = threadIdx.x;
  const int w = tid >> 6, l = tid & 63, l15 = l & 15, g = l >> 4;

  __shared__ __align__(16) unsigned short V2[64 * 256];  // 32 KB, swizzled bf16 [t][n]
  __shared__ __align__(16) unsigned int Hr[32 * HROW];   // 16.9 KB
  __shared__ __align__(16) float Lexf[64 * 8];           // 2 KB

  const f32x4 adv = *(const f32x4*)&Ad[4 * l];

  // ---- loop-invariant fragments in registers (loaded once per block) ----
  bf16x8 ctf[8][2];     // C^T slice: o in [32w, 32w+32)
  #pragma unroll
  for (int kt = 0; kt < 8; ++kt)
    #pragma unroll
    for (int ot = 0; ot < 2; ++ot)
      ctf[kt][ot] = *(const bf16x8*)&CT[(w * 32 + ot * 16 + l15) * NS + kt * 32 + g * 8];
  bf16x8 wf[2][8];      // W slice: o in [32w, 32w+32)
  #pragma unroll
  for (int nt = 0; nt < 2; ++nt)
    #pragma unroll
    for (int kt = 0; kt < 8; ++kt)
      wf[nt][kt] = *(const bf16x8*)&Wb[(w * 32 + nt * 16 + l15) * NS + kt * 32 + g * 8];
  f32x4 pwv[8];         // PW rows tp = r*4+w
  #pragma unroll
  for (int r = 0; r < 8; ++r)
    pwv[r] = *(const f32x4*)&PWf[(r * 4 + w) * 256 + 4 * l];
  const float ga0 = lng[w * 32 + l15],      be0 = lnb[w * 32 + l15];
  const float ga1 = lng[w * 32 + 16 + l15], be1 = lnb[w * 32 + 16 + l15];
  const float bia0 = bias[w * 32 + l15];
  const float bia1 = bias[w * 32 + 16 + l15];

  u32x4 st0, st1, st2, st3, st4, st5, st6, st7;
  f32x4 sd;

#define LOAD_ST(KC) do {                                                    \
    const unsigned int* scb_ = S + (size_t)(b * NCHUNK + (KC)) * SCHUNK;    \
    st0 = *(const u32x4*)&scb_[0 * 1024 + tid * 4];                         \
    st1 = *(const u32x4*)&scb_[1 * 1024 + tid * 4];                         \
    st2 = *(const u32x4*)&scb_[2 * 1024 + tid * 4];                         \
    st3 = *(const u32x4*)&scb_[3 * 1024 + tid * 4];                         \
    st4 = *(const u32x4*)&scb_[4 * 1024 + tid * 4];                         \
    st5 = *(const u32x4*)&scb_[5 * 1024 + tid * 4];                         \
    st6 = *(const u32x4*)&scb_[6 * 1024 + tid * 4];                         \
    st7 = *(const u32x4*)&scb_[7 * 1024 + tid * 4];                         \
    sd  = *(const f32x4*)&carry[((size_t)b * NCHUNK + (KC)) * NS + 4 * l];  \
  } while (0)

  // thread owns t-pair row tp = RR*4+w, cols n = 4l..4l+3; writes rows 2tp, 2tp+1
#define CORRECT_ROW(QV, RR) do {                                            \
    const float e00 = sd[0] * pwv[RR][0];                                   \
    const float e01 = sd[1] * pwv[RR][1];                                   \
    const float e02 = sd[2] * pwv[RR][2];                                   \
    const float e03 = sd[3] * pwv[RR][3];                                   \
    const float lo0 = __uint_as_float(QV[0] << 16) + e00;                   \
    const float hi0 = __uint_as_float(QV[0] & 0xffff0000u) + e00 * adv[0];  \
    const float lo1 = __uint_as_float(QV[1] << 16) + e01;                   \
    const float hi1 = __uint_as_float(QV[1] & 0xffff0000u) + e01 * adv[1];  \
    const float lo2 = __uint_as_float(QV[2] << 16) + e02;                   \
    const float hi2 = __uint_as_float(QV[2] & 0xffff0000u) + e02 * adv[2];  \
    const float lo3 = __uint_as_float(QV[3] << 16) + e03;                   \
    const float hi3 = __uint_as_float(QV[3] & 0xffff0000u) + e03 * adv[3];  \
    const int t0_ = ((RR) * 4 + w) * 2;                                     \
    const int t1_ = t0_ + 1;                                                \
    uint2 wlo; wlo.x = pk2(lo0, lo1); wlo.y = pk2(lo2, lo3);                \
    uint2 whi; whi.x = pk2(hi0, hi1); whi.y = pk2(hi2, hi3);                \
    *(uint2*)&V2[t0_ * 256 + ((((l >> 1) ^ ((t0_ & 7) << 2)) << 3) | ((l & 1) << 2))] = wlo; \
    *(uint2*)&V2[t1_ * 256 + ((((l >> 1) ^ ((t1_ & 7) << 2)) << 3) | ((l & 1) << 2))] = whi; \
  } while (0)

#define CORRECT_STORE() do {                                                \
    CORRECT_ROW(st0, 0); CORRECT_ROW(st1, 1);                               \
    CORRECT_ROW(st2, 2); CORRECT_ROW(st3, 3);                               \
    CORRECT_ROW(st4, 4); CORRECT_ROW(st5, 5);                               \
    CORRECT_ROW(st6, 6); CORRECT_ROW(st7, 7);                               \
  } while (0)

  // ---- prologue: load+correct chunk kc0 -> V2; issue kc0+1 loads ----
  LOAD_ST(kc0);
  CORRECT_STORE();
  LOAD_ST(kc0 + 1);
  rawbar();

  #pragma unroll 1
  for (int i = 0; i < NCHK; ++i) {
    const int kc = kc0 + i;

    // ---- B: y-GEMM (wave w: all 64 t x 32 o) + LN partials ----
    f32x4 yac[4][2] = {};
    #pragma unroll
    for (int kt = 0; kt < 8; ++kt) {
      bf16x8 As[4];
      #pragma unroll
      for (int mt = 0; mt < 4; ++mt) {
        const int t = mt * 16 + l15;
        As[mt] = *(const bf16x8*)&V2[t * 256 + (((kt * 4 + g) ^ ((t & 7) << 2)) << 3)];
      }
      #pragma unroll
      for (int ot = 0; ot < 2; ++ot)
        #pragma unroll
        for (int mt = 0; mt < 4; ++mt)
          yac[mt][ot] = __builtin_amdgcn_mfma_f32_16x16x32_bf16(As[mt], ctf[kt][ot], yac[mt][ot], 0, 0, 0);
    }
    #pragma unroll
    for (int mt = 0; mt < 4; ++mt)
      #pragma unroll
      for (int r = 0; r < 4; ++r) {
        float s1 = yac[mt][0][r] + yac[mt][1][r];
        float s2 = yac[mt][0][r] * yac[mt][0][r] + yac[mt][1][r] * yac[mt][1][r];
        #pragma unroll
        for (int d = 1; d < 16; d <<= 1) { s1 += __shfl_xor(s1, d); s2 += __shfl_xor(s2, d); }
        if (l15 == 0) {
          const int t = mt * 16 + g * 4 + r;
          *(float2*)&Lexf[t * 8 + w * 2] = make_float2(s1, s2);
        }
      }
    rawbar();   // C: Lex visible; V2 fully read

    // ---- D: LN finish + SiLU -> Hr; staged correction for next chunk -> V2 ----
    #pragma unroll
    for (int mt = 0; mt < 4; ++mt) {
      float mu[4], rs[4];
      #pragma unroll
      for (int r = 0; r < 4; ++r) {
        const int t = mt * 16 + g * 4 + r;
        const float4 f0 = *(const float4*)&Lexf[t * 8];
        const float4 f1 = *(const float4*)&Lexf[t * 8 + 4];
        const float m = (f0.x + f0.z + f1.x + f1.z) * (1.0f / 128.0f);
        const float va = (f0.y + f0.w + f1.y + f1.w) * (1.0f / 128.0f) - m * m;
        mu[r] = m;
        rs[r] = rsqrtf(va + 1e-5f);
      }
      #pragma unroll
      for (int ot = 0; ot < 2; ++ot) {
        const int o = w * 32 + ot * 16 + l15;
        const float ga = ot ? ga1 : ga0;
        const float be = ot ? be1 : be0;
        #pragma unroll
        for (int rp = 0; rp < 2; ++rp) {
          float h0 = (yac[mt][ot][rp * 2] - mu[rp * 2]) * rs[rp * 2] * ga + be;
          h0 = h0 * __builtin_amdgcn_rcpf(1.0f + __expf(-h0));
          float h1 = (yac[mt][ot][rp * 2 + 1] - mu[rp * 2 + 1]) * rs[rp * 2 + 1] * ga + be;
          h1 = h1 * __builtin_amdgcn_rcpf(1.0f + __expf(-h1));
          const int t2 = mt * 8 + g * 2 + rp;
          Hr[t2 * HROW + o] = pk2(h0, h1);
        }
      }
    }
    if (i + 1 < NCHK) {
      CORRECT_STORE();   // overwrites V2 with chunk i+1 (fully read at barC)
      if (i + 2 < NCHK) LOAD_ST(kc + 2);
    }
    rawbar();   // E: Hr + next-chunk V2 visible

    // ---- F: out-GEMM (wave w: 32 t2 x 32 o) -> direct stores ----
    {
      f32x4 oac[2][2] = {};
      #pragma unroll
      for (int kt = 0; kt < 8; ++kt) {
        bf16x8 Aa0, Aa1;
        {
          union { bf16x8 v; u32x4 u; } Ax;
          Ax.u = *(const u32x4*)&Hr[(l15) * HROW + kt * 16 + g * 4];
          Aa0 = Ax.v;
          Ax.u = *(const u32x4*)&Hr[(16 + l15) * HROW + kt * 16 + g * 4];
          Aa1 = Ax.v;
        }
        #pragma unroll
        for (int nt = 0; nt < 2; ++nt) {
          oac[0][nt] = __builtin_amdgcn_mfma_f32_16x16x32_bf16(Aa0, wf[nt][kt], oac[0][nt], 0, 0, 0);
          oac[1][nt] = __builtin_amdgcn_mfma_f32_16x16x32_bf16(Aa1, wf[nt][kt], oac[1][nt], 0, 0, 0);
        }
      }
      #pragma unroll
      for (int nt = 0; nt < 2; ++nt) {
        const int o = w * 32 + nt * 16 + l15;
        const float bia = nt ? bia1 : bia0;
        #pragma unroll
        for (int mt = 0; mt < 2; ++mt) {
          float4 q;
          q.x = oac[mt][nt][0] + bia;
          q.y = oac[mt][nt][1] + bia;
          q.z = oac[mt][nt][2] + bia;
          q.w = oac[mt][nt][3] + bia;
          *(float4*)(out + ((size_t)(b * OCH + o)) * THALF + kc * 32 + mt * 16 + g * 4) = q;
        }
      }
    }
  }
#undef LOAD_ST
#undef CORRECT_ROW
#undef CORRECT_STORE
}

// ---------------- launch ----------------
extern "C" void kernel_launch(void* const* d_in, const int* in_sizes, int n_in,
                              void* d_out, int out_size, void* d_ws, size_t ws_size,
                              hipStream_t stream) {
  const float* x    = (const float*)d_in[0];
  const float* rl   = (const float*)d_in[1];
  const float* Bc   = (const float*)d_in[2];
  const float* Cm   = (const float*)d_in[3];
  const float* lng  = (const float*)d_in[4];
  const float* lnb  = (const float*)d_in[5];
  const float* W    = (const float*)d_in[6];
  const float* bias = (const float*)d_in[7];
  float* out = (float*)d_out;

  char* ws = (char*)d_ws;
  unsigned short* BdT = (unsigned short*)(ws);            // 64 KB
  unsigned short* CT  = (unsigned short*)(ws + 65536);    // 64 KB
  unsigned short* Wb  = (unsigned short*)(ws + 131072);   // 64 KB
  float* Ad    = (float*)(ws + 196608);                   // 1 KB
  float* rL    = (float*)(ws + 197632);                   // 1 KB
  float* PWf   = (float*)(ws + 198656);                   // 32 KB
  float* carry = (float*)(ws + 231424);                   // 2 MB
  unsigned int* S = (unsigned int*)(ws + 231424 + 2097152); // 64 MB

  k_prep<<<417, 256, 0, stream>>>(rl, Bc, Cm, W, BdT, CT, Wb, Ad, rL, PWf);
  k_scan<<<BATCH * NCHUNK, 512, 0, stream>>>(x, BdT, Ad, S, carry);
  k_combine<<<64, 256, 0, stream>>>(carry, rL);
  k_apply<<<BATCH * (NCHUNK / NCHK), 256, 0, stream>>>(S, CT, Wb, PWf, Ad, carry,
                                                       lng, lnb, bias, out);
}

// Round 16
// 100.707 us; speedup vs baseline: 1.1165x; 1.1165x over previous
//
#include <hip/hip_runtime.h>

#define BATCH 8
#define CIN 128
#define OCH 128
#define T_LEN 16384
#define NS 256
#define CHUNK 64
#define NCHUNK (T_LEN / CHUNK)   // 256
#define THALF (T_LEN / 2)        // 8192
#define SCHUNK 8192              // u32 per chunk image in global: 32 rows x 256 n
#define HROW 132                 // Hr row stride (u32)
#define NCHK 8                   // chunks per apply block (4 pairs) -> grid 256 = 1 block/CU

typedef __attribute__((ext_vector_type(8))) short bf16x8;
typedef __attribute__((ext_vector_type(4))) float f32x4;
typedef __attribute__((ext_vector_type(4))) unsigned int u32x4;

__device__ __forceinline__ unsigned int pk2(float lo, float hi) {
  unsigned int d;
  asm("v_cvt_pk_bf16_f32 %0, %1, %2" : "=v"(d) : "v"(lo), "v"(hi));
  return d;
}
__device__ __forceinline__ unsigned short f2bf(float f) {
  unsigned int u = __float_as_uint(f);
  u += 0x7fffu + ((u >> 16) & 1u);
  return (unsigned short)(u >> 16);
}
__device__ __forceinline__ float softplusf_(float v) {
  return (v > 20.0f) ? v : log1pf(expf(v));
}
// barrier that does NOT drain vmcnt (keeps global prefetch in flight)
__device__ __forceinline__ void rawbar() {
  __builtin_amdgcn_sched_barrier(0);
  asm volatile("s_waitcnt lgkmcnt(0)" ::: "memory");
  __builtin_amdgcn_sched_barrier(0);
  __builtin_amdgcn_s_barrier();
  __builtin_amdgcn_sched_barrier(0);
}

// ---------------- prep: weights -> bf16, A_d, A_d^L, PWf[tp][n] = A_n^(2tp+1) ----------------
__global__ __launch_bounds__(256) void k_prep(
    const float* __restrict__ rl, const float* __restrict__ Bc,
    const float* __restrict__ Cm, const float* __restrict__ W,
    unsigned short* __restrict__ BdT, unsigned short* __restrict__ CT,
    unsigned short* __restrict__ Wb, float* __restrict__ Ad, float* __restrict__ rL,
    float* __restrict__ PWf)
{
  const int tid = blockIdx.x * 256 + threadIdx.x;
  if (tid < NS * CIN) {                       // BdT[n][c] = B_c[c][n] * (A_d-1)/lam
    const int n = tid >> 7, c = tid & 127;
    float lam = -softplusf_(rl[n]);
    float ad = expf(lam);
    float sc = (ad - 1.0f) / lam;
    BdT[tid] = f2bf(Bc[c * NS + n] * sc);
  } else if (tid < 2 * NS * CIN) {            // CT[o][n] = C[n][o]
    const int i = tid - NS * CIN;
    const int o = i >> 8, n = i & 255;
    CT[i] = f2bf(Cm[n * OCH + o]);
  } else if (tid < 3 * NS * CIN) {            // Wb[o][c2] = W[o][c2]
    const int i = tid - 2 * NS * CIN;
    Wb[i] = f2bf(W[i]);
  } else if (tid < 3 * NS * CIN + NS) {
    const int n = tid - 3 * NS * CIN;
    float lam = -softplusf_(rl[n]);
    Ad[n] = expf(lam);
    rL[n] = expf(lam * (float)CHUNK);
  } else if (tid < 3 * NS * CIN + NS + 32 * NS) {   // PWf[tp][n] = A_n^(2tp+1)
    const int i = tid - (3 * NS * CIN + NS);
    const int tp = i >> 8, n = i & 255;
    float lam = -softplusf_(rl[n]);
    PWf[i] = expf(lam * (float)(2 * tp + 1));
  }
}

// ---------------- chunk-carry combine: Hillis-Steele, 256 blocks (8 n per block) ----------------
// R16: was 64 blocks (25% of the chip); now BATCH x 32 n-groups = 256 blocks, rp[8], Y 8 KB.
__global__ __launch_bounds__(256) void k_combine(float* __restrict__ carry,
                                                 const float* __restrict__ rL)
{
  const int b = blockIdx.x >> 5;
  const int ng = blockIdx.x & 31;     // n-group of 8
  const int t = threadIdx.x;          // chunk index
  __shared__ float Y[8][NCHUNK];
  float* base = carry + ((size_t)b * NCHUNK + t) * NS + ng * 8;
  #pragma unroll
  for (int i4 = 0; i4 < 2; ++i4) {
    float4 q = *(const float4*)(base + i4 * 4);
    Y[i4 * 4 + 0][t] = q.x; Y[i4 * 4 + 1][t] = q.y;
    Y[i4 * 4 + 2][t] = q.z; Y[i4 * 4 + 3][t] = q.w;
  }
  float rp[8];
  #pragma unroll
  for (int i = 0; i < 8; ++i) rp[i] = rL[ng * 8 + i];
  __syncthreads();
  for (int d = 1; d < NCHUNK; d <<= 1) {
    float tmp[8];
    #pragma unroll
    for (int i = 0; i < 8; ++i) tmp[i] = (t >= d) ? Y[i][t - d] : 0.0f;
    __syncthreads();
    #pragma unroll
    for (int i = 0; i < 8; ++i) { Y[i][t] += rp[i] * tmp[i]; rp[i] *= rp[i]; }
    __syncthreads();
  }
  const int tm = (t == 0) ? 0 : (t - 1);
  #pragma unroll
  for (int i4 = 0; i4 < 2; ++i4) {
    float a = Y[i4 * 4 + 0][tm], bb = Y[i4 * 4 + 1][tm];
    float c = Y[i4 * 4 + 2][tm], dd = Y[i4 * 4 + 3][tm];
    float4 q;
    q.x = (t == 0) ? 0.0f : a;  q.y = (t == 0) ? 0.0f : bb;
    q.z = (t == 0) ? 0.0f : c;  q.w = (t == 0) ? 0.0f : dd;
    *(float4*)(base + i4 * 4) = q;
  }
}

// ---------------- k_scan: (512,4) + reduced peak pressure (in-loop Bf, post-GEMM consts) ----
// R16: keep R13's occupancy (4 blocks/CU) but pull peak live regs under the 64 cap:
// Bf fragments loaded inside the GEMM loop (each used once per block) and scan constants
// computed AFTER the GEMM so their 18 registers don't overlap the MFMA phase.
__global__ __launch_bounds__(512, 4) void k_scan(
    const float* __restrict__ x,
    const unsigned short* __restrict__ BdT,
    const float* __restrict__ Ad,
    unsigned int* __restrict__ s0,
    float* __restrict__ carry)
{
  const int bid = blockIdx.x;
  const int b = bid >> 8;
  const int kc = bid & 255;
  const int tid = threadIdx.x;
  const int w = tid >> 6, l = tid & 63, l15 = l & 15, g = l >> 4;

  __shared__ __align__(16) unsigned int Xt[64 * 64];  // [t][c2 ^ ((t&7)<<2)] packed bf16 pairs

  // ---- stage x: thread -> (c2 = w*8 + (l&7), t-block = (l>>3)*8): contiguous 32B loads ----
  {
    const int c2 = w * 8 + (l & 7);
    const int t0b = (l >> 3) * 8;
    const float* r0 = x + ((size_t)(b * CIN + 2 * c2)) * T_LEN + kc * CHUNK + t0b;
    const f32x4 xa0 = *(const f32x4*)r0;
    const f32x4 xa1 = *(const f32x4*)(r0 + 4);
    const f32x4 xb0 = *(const f32x4*)(r0 + T_LEN);
    const f32x4 xb1 = *(const f32x4*)(r0 + T_LEN + 4);
    #pragma unroll
    for (int k = 0; k < 8; ++k) {
      const int t = t0b + k;
      const float va = (k < 4) ? xa0[k & 3] : xa1[k & 3];
      const float vb = (k < 4) ? xb0[k & 3] : xb1[k & 3];
      Xt[t * 64 + (c2 ^ ((t & 7) << 2))] = pk2(va, vb);
    }
  }
  __syncthreads();

  // ---- v-GEMM (Bf in-loop) ----
  f32x4 vac[4][2] = {};
  #pragma unroll
  for (int kt = 0; kt < 4; ++kt) {
    bf16x8 afr[4];
    #pragma unroll
    for (int mt = 0; mt < 4; ++mt)
      afr[mt] = *(const bf16x8*)&Xt[(mt * 16 + l15) * 64 + ((kt * 16 + g * 4) ^ ((l15 & 7) << 2))];
    #pragma unroll
    for (int nt = 0; nt < 2; ++nt) {
      const bf16x8 bf = *(const bf16x8*)&BdT[(w * 32 + nt * 16 + l15) * CIN + kt * 32 + g * 8];
      #pragma unroll
      for (int mt = 0; mt < 4; ++mt)
        vac[mt][nt] = __builtin_amdgcn_mfma_f32_16x16x32_bf16(afr[mt], bf, vac[mt][nt], 0, 0, 0);
    }
  }

  // ---- scan constants (after GEMM: shrink peak live set) ----
  float A1[2], A2[2], A3[2], A4[2], A8[2], A16[2], A4G[2], M1[2], M2[2];
  #pragma unroll
  for (int nt = 0; nt < 2; ++nt) {
    const float a1 = Ad[w * 32 + nt * 16 + l15];
    A1[nt] = a1; A2[nt] = a1 * a1; A3[nt] = A2[nt] * a1; A4[nt] = A2[nt] * A2[nt];
    A8[nt] = A4[nt] * A4[nt]; A16[nt] = A8[nt] * A8[nt];
    float a4g = 1.0f;
    if (g & 1) a4g *= A4[nt];
    if (g & 2) a4g *= A8[nt];
    A4G[nt] = a4g;
    M1[nt] = (g >= 1) ? A4[nt] : 0.0f;
    M2[nt] = (g >= 2) ? A8[nt] : 0.0f;
  }

  // ---- in-register scan over t, seed 0 ----
  float crv[2];
  #pragma unroll
  for (int nt = 0; nt < 2; ++nt) {
    float cr = 0.0f;
    #pragma unroll
    for (int mt = 0; mt < 4; ++mt) {
      const float p0 = vac[mt][nt][0];
      const float p1 = fmaf(A1[nt], p0, vac[mt][nt][1]);
      const float p2 = fmaf(A1[nt], p1, vac[mt][nt][2]);
      const float p3 = fmaf(A1[nt], p2, vac[mt][nt][3]);
      float c0 = p3;
      float u = __shfl_up(c0, 16);
      c0 = fmaf(M1[nt], u, c0);
      u = __shfl_up(c0, 32);
      c0 = fmaf(M2[nt], u, c0);
      float e = __shfl_up(c0, 16);
      e = (g == 0) ? 0.0f : e;
      const float seed = fmaf(A4G[nt], cr, e);
      vac[mt][nt][0] = fmaf(A1[nt], seed, p0);
      vac[mt][nt][1] = fmaf(A2[nt], seed, p1);
      vac[mt][nt][2] = fmaf(A3[nt], seed, p2);
      vac[mt][nt][3] = fmaf(A4[nt], seed, p3);
      const float ctop = __shfl(c0, 48 + l15);
      cr = fmaf(A16[nt], cr, ctop);
    }
    crv[nt] = cr;
  }

  // ---- store packed s0 [tp][n] (linear, coalesced) + totals ----
  unsigned int* sc = s0 + (size_t)(b * NCHUNK + kc) * SCHUNK;
  #pragma unroll
  for (int mt = 0; mt < 4; ++mt)
    #pragma unroll
    for (int nt = 0; nt < 2; ++nt) {
      const int n = w * 32 + nt * 16 + l15;
      #pragma unroll
      for (int rp = 0; rp < 2; ++rp) {
        const int tp = mt * 8 + g * 2 + rp;
        sc[tp * 256 + n] = pk2(vac[mt][nt][rp * 2], vac[mt][nt][rp * 2 + 1]);
      }
    }
  if (g == 0) {
    #pragma unroll
    for (int nt = 0; nt < 2; ++nt)
      carry[((size_t)b * NCHUNK + kc) * NS + (w * 32 + nt * 16 + l15)] = crv[nt];
  }
}

// ---------------- k_apply: PAIRED chunks (R13 exact) ----------------
__global__ __launch_bounds__(512, 2) void k_apply(
    const unsigned int* __restrict__ S,
    const unsigned short* __restrict__ CT,
    const unsigned short* __restrict__ Wb,
    const float* __restrict__ PWf,
    const float* __restrict__ Ad,
    const float* __restrict__ carry,
    const float* __restrict__ lng, const float* __restrict__ lnb,
    const float* __restrict__ bias,
    float* __restrict__ out)
{
  const int bid = blockIdx.x;
  const int b = bid / (NCHUNK / NCHK);
  const int kc0 = (bid % (NCHUNK / NCHK)) * NCHK;
  const int tid = threadIdx.x;
  const int w = tid >> 6, l = tid & 63, l15 = l & 15, g = l >> 4;
  const int tt = w >> 2, oq = w & 3;

  __shared__ __align__(16) unsigned short V2a[64 * 256];  // 32 KB, swizzled bf16 [t][n]
  __shared__ __align__(16) unsigned short V2b[64 * 256];  // 32 KB
  __shared__ __align__(16) unsigned int Hra[32 * HROW];   // 16.9 KB
  __shared__ __align__(16) unsigned int Hrb[32 * HROW];   // 16.9 KB
  __shared__ __align__(16) float Lexf[2][64 * 8];         // 4 KB

  const f32x4 adv = *(const f32x4*)&Ad[4 * l];

  // ---- loop-invariant fragments in registers (loaded ONCE per block, amortized over 8 chunks) ----
  bf16x8 ctf[8][2];
  #pragma unroll
  for (int kt = 0; kt < 8; ++kt)
    #pragma unroll
    for (int ot = 0; ot < 2; ++ot)
      ctf[kt][ot] = *(const bf16x8*)&CT[(oq * 32 + ot * 16 + l15) * NS + kt * 32 + g * 8];
  bf16x8 wf[8];
  #pragma unroll
  for (int kt = 0; kt < 8; ++kt)
    wf[kt] = *(const bf16x8*)&Wb[(w * 16 + l15) * NS + kt * 32 + g * 8];
  f32x4 pwv[4];
  #pragma unroll
  for (int r = 0; r < 4; ++r)
    pwv[r] = *(const f32x4*)&PWf[(r * 8 + w) * 256 + 4 * l];
  const float ga0 = lng[oq * 32 + l15],      be0 = lnb[oq * 32 + l15];
  const float ga1 = lng[oq * 32 + 16 + l15], be1 = lnb[oq * 32 + 16 + l15];
  const float bia = bias[w * 16 + l15];

  u32x4 sa0, sa1, sa2, sa3, sb0, sb1, sb2, sb3;
  f32x4 sda, sdb;

#define LOAD_ST(KC, T0, T1, T2, T3, SD) do {                                \
    const unsigned int* scb_ = S + (size_t)(b * NCHUNK + (KC)) * SCHUNK;    \
    T0 = *(const u32x4*)&scb_[0 * 2048 + tid * 4];                          \
    T1 = *(const u32x4*)&scb_[1 * 2048 + tid * 4];                          \
    T2 = *(const u32x4*)&scb_[2 * 2048 + tid * 4];                          \
    T3 = *(const u32x4*)&scb_[3 * 2048 + tid * 4];                          \
    SD = *(const f32x4*)&carry[((size_t)b * NCHUNK + (KC)) * NS + 4 * l];   \
  } while (0)

  // thread owns t-pair rows tp = RR*8+w, cols n = 4l..4l+3; writes rows 2tp (lo) and 2tp+1 (hi)
#define CORRECT_ROW(DSTV, QV, RR, SD) do {                                  \
    const float e00 = SD[0] * pwv[RR][0];                                   \
    const float e01 = SD[1] * pwv[RR][1];                                   \
    const float e02 = SD[2] * pwv[RR][2];                                   \
    const float e03 = SD[3] * pwv[RR][3];                                   \
    const float lo0 = __uint_as_float(QV[0] << 16) + e00;                   \
    const float hi0 = __uint_as_float(QV[0] & 0xffff0000u) + e00 * adv[0];  \
    const float lo1 = __uint_as_float(QV[1] << 16) + e01;                   \
    const float hi1 = __uint_as_float(QV[1] & 0xffff0000u) + e01 * adv[1];  \
    const float lo2 = __uint_as_float(QV[2] << 16) + e02;                   \
    const float hi2 = __uint_as_float(QV[2] & 0xffff0000u) + e02 * adv[2];  \
    const float lo3 = __uint_as_float(QV[3] << 16) + e03;                   \
    const float hi3 = __uint_as_float(QV[3] & 0xffff0000u) + e03 * adv[3];  \
    const int t0_ = ((RR) * 8 + w) * 2;                                     \
    const int t1_ = t0_ + 1;                                                \
    uint2 wlo; wlo.x = pk2(lo0, lo1); wlo.y = pk2(lo2, lo3);                \
    uint2 whi; whi.x = pk2(hi0, hi1); whi.y = pk2(hi2, hi3);                \
    *(uint2*)&DSTV[t0_ * 256 + ((((l >> 1) ^ ((t0_ & 7) << 2)) << 3) | ((l & 1) << 2))] = wlo; \
    *(uint2*)&DSTV[t1_ * 256 + ((((l >> 1) ^ ((t1_ & 7) << 2)) << 3) | ((l & 1) << 2))] = whi; \
  } while (0)

#define CORRECT_STORE(DSTV, T0, T1, T2, T3, SD) do {                        \
    CORRECT_ROW(DSTV, T0, 0, SD);                                           \
    CORRECT_ROW(DSTV, T1, 1, SD);                                           \
    CORRECT_ROW(DSTV, T2, 2, SD);                                           \
    CORRECT_ROW(DSTV, T3, 3, SD);                                           \
  } while (0)

  // y-GEMM over one V2 buffer -> yac + LN partials into Lexf[IDX]
#define YGEMM(V2X, YAC, IDX) do {                                           \
    _Pragma("unroll")                                                       \
    for (int kt = 0; kt < 8; ++kt) {                                        \
      bf16x8 As0, As1;                                                      \
      {                                                                     \
        const int t0 = tt * 32 + l15;                                       \
        As0 = *(const bf16x8*)&V2X[t0 * 256 + (((kt * 4 + g) ^ ((t0 & 7) << 2)) << 3)]; \
        const int t1 = tt * 32 + 16 + l15;                                  \
        As1 = *(const bf16x8*)&V2X[t1 * 256 + (((kt * 4 + g) ^ ((t1 & 7) << 2)) << 3)]; \
      }                                                                     \
      _Pragma("unroll")                                                     \
      for (int ot = 0; ot < 2; ++ot) {                                      \
        YAC[0][ot] = __builtin_amdgcn_mfma_f32_16x16x32_bf16(As0, ctf[kt][ot], YAC[0][ot], 0, 0, 0); \
        YAC[1][ot] = __builtin_amdgcn_mfma_f32_16x16x32_bf16(As1, ctf[kt][ot], YAC[1][ot], 0, 0, 0); \
      }                                                                     \
    }                                                                       \
    _Pragma("unroll")                                                       \
    for (int mt = 0; mt < 2; ++mt)                                          \
      _Pragma("unroll")                                                     \
      for (int r = 0; r < 4; ++r) {                                         \
        float s1 = YAC[mt][0][r] + YAC[mt][1][r];                           \
        float s2 = YAC[mt][0][r] * YAC[mt][0][r] + YAC[mt][1][r] * YAC[mt][1][r]; \
        _Pragma("unroll")                                                   \
        for (int d = 1; d < 16; d <<= 1) { s1 += __shfl_xor(s1, d); s2 += __shfl_xor(s2, d); } \
        if (l15 == 0) {                                                     \
          const int t = tt * 32 + mt * 16 + g * 4 + r;                      \
          *(float2*)&Lexf[IDX][t * 8 + oq * 2] = make_float2(s1, s2);       \
        }                                                                   \
      }                                                                     \
  } while (0)

  // LN finish + SiLU from YAC -> HRX
#define LNSILU(HRX, YAC, IDX) do {                                          \
    _Pragma("unroll")                                                       \
    for (int mt = 0; mt < 2; ++mt) {                                        \
      float mu[4], rs[4];                                                   \
      _Pragma("unroll")                                                     \
      for (int r = 0; r < 4; ++r) {                                         \
        const int t = tt * 32 + mt * 16 + g * 4 + r;                        \
        const float4 f0 = *(const float4*)&Lexf[IDX][t * 8];                \
        const float4 f1 = *(const float4*)&Lexf[IDX][t * 8 + 4];            \
        const float m = (f0.x + f0.z + f1.x + f1.z) * (1.0f / 128.0f);      \
        const float va = (f0.y + f0.w + f1.y + f1.w) * (1.0f / 128.0f) - m * m; \
        mu[r] = m;                                                          \
        rs[r] = rsqrtf(va + 1e-5f);                                         \
      }                                                                     \
      _Pragma("unroll")                                                     \
      for (int ot = 0; ot < 2; ++ot) {                                      \
        const int o = oq * 32 + ot * 16 + l15;                              \
        const float ga = ot ? ga1 : ga0;                                    \
        const float be = ot ? be1 : be0;                                    \
        _Pragma("unroll")                                                   \
        for (int rp = 0; rp < 2; ++rp) {                                    \
          float h0 = (YAC[mt][ot][rp * 2] - mu[rp * 2]) * rs[rp * 2] * ga + be; \
          h0 = h0 * __builtin_amdgcn_rcpf(1.0f + __expf(-h0));              \
          float h1 = (YAC[mt][ot][rp * 2 + 1] - mu[rp * 2 + 1]) * rs[rp * 2 + 1] * ga + be; \
          h1 = h1 * __builtin_amdgcn_rcpf(1.0f + __expf(-h1));              \
          const int t2 = tt * 16 + mt * 8 + g * 2 + rp;                     \
          HRX[t2 * HROW + o] = pk2(h0, h1);                                 \
        }                                                                   \
      }                                                                     \
    }                                                                       \
  } while (0)

  // out-GEMM from HRX -> global at chunk KC
#define OUTGEMM(HRX, KC) do {                                               \
    f32x4 oac0 = {}, oac1 = {};                                             \
    _Pragma("unroll")                                                       \
    for (int kt = 0; kt < 8; ++kt) {                                        \
      bf16x8 Aa0, Aa1;                                                      \
      {                                                                     \
        union { bf16x8 v; u32x4 u; } Ax;                                    \
        Ax.u = *(const u32x4*)&HRX[(l15) * HROW + kt * 16 + g * 4];         \
        Aa0 = Ax.v;                                                         \
        Ax.u = *(const u32x4*)&HRX[(16 + l15) * HROW + kt * 16 + g * 4];    \
        Aa1 = Ax.v;                                                         \
      }                                                                     \
      oac0 = __builtin_amdgcn_mfma_f32_16x16x32_bf16(Aa0, wf[kt], oac0, 0, 0, 0); \
      oac1 = __builtin_amdgcn_mfma_f32_16x16x32_bf16(Aa1, wf[kt], oac1, 0, 0, 0); \
    }                                                                       \
    const int o = w * 16 + l15;                                             \
    float4 q0;                                                              \
    q0.x = oac0[0] + bia; q0.y = oac0[1] + bia;                             \
    q0.z = oac0[2] + bia; q0.w = oac0[3] + bia;                             \
    *(float4*)(out + ((size_t)(b * OCH + o)) * THALF + (KC) * 32 + g * 4) = q0; \
    float4 q1;                                                              \
    q1.x = oac1[0] + bia; q1.y = oac1[1] + bia;                             \
    q1.z = oac1[2] + bia; q1.w = oac1[3] + bia;                             \
    *(float4*)(out + ((size_t)(b * OCH + o)) * THALF + (KC) * 32 + 16 + g * 4) = q1; \
  } while (0)

  // ---- prologue: pair 0 -> V2a/V2b; prefetch pair 1 into registers ----
  LOAD_ST(kc0 + 0, sa0, sa1, sa2, sa3, sda);
  CORRECT_STORE(V2a, sa0, sa1, sa2, sa3, sda);
  LOAD_ST(kc0 + 1, sb0, sb1, sb2, sb3, sdb);
  CORRECT_STORE(V2b, sb0, sb1, sb2, sb3, sdb);
  LOAD_ST(kc0 + 2, sa0, sa1, sa2, sa3, sda);
  LOAD_ST(kc0 + 3, sb0, sb1, sb2, sb3, sdb);
  rawbar();

  #pragma unroll 1
  for (int i = 0; i < NCHK / 2; ++i) {
    const int kcA = kc0 + 2 * i;
    const int kcB = kcA + 1;

    // ---- B: two independent y-GEMMs + LN partials ----
    f32x4 yacA[2][2] = {};
    f32x4 yacB[2][2] = {};
    YGEMM(V2a, yacA, 0);
    YGEMM(V2b, yacB, 1);
    rawbar();   // C: Lex visible; V2a/V2b fully read

    // ---- D: LN/SiLU both chunks; stage next pair into V2; prefetch pair i+2 ----
    LNSILU(Hra, yacA, 0);
    LNSILU(Hrb, yacB, 1);
    if (i + 1 < NCHK / 2) {
      CORRECT_STORE(V2a, sa0, sa1, sa2, sa3, sda);
      CORRECT_STORE(V2b, sb0, sb1, sb2, sb3, sdb);
      if (i + 2 < NCHK / 2) {
        LOAD_ST(kcA + 4, sa0, sa1, sa2, sa3, sda);
        LOAD_ST(kcB + 4, sb0, sb1, sb2, sb3, sdb);
      }
    }
    rawbar();   // E: Hr + next-pair V2 visible

    // ---- F: two independent out-GEMMs -> direct stores ----
    OUTGEMM(Hra, kcA);
    OUTGEMM(Hrb, kcB);
  }
#undef LOAD_ST
#undef CORRECT_ROW
#undef CORRECT_STORE
#undef YGEMM
#undef LNSILU
#undef OUTGEMM
}

// ---------------- launch ----------------
extern "C" void kernel_launch(void* const* d_in, const int* in_sizes, int n_in,
                              void* d_out, int out_size, void* d_ws, size_t ws_size,
                              hipStream_t stream) {
  const float* x    = (const float*)d_in[0];
  const float* rl   = (const float*)d_in[1];
  const float* Bc   = (const float*)d_in[2];
  const float* Cm   = (const float*)d_in[3];
  const float* lng  = (const float*)d_in[4];
  const float* lnb  = (const float*)d_in[5];
  const float* W    = (const float*)d_in[6];
  const float* bias = (const float*)d_in[7];
  float* out = (float*)d_out;

  char* ws = (char*)d_ws;
  unsigned short* BdT = (unsigned short*)(ws);            // 64 KB
  unsigned short* CT  = (unsigned short*)(ws + 65536);    // 64 KB
  unsigned short* Wb  = (unsigned short*)(ws + 131072);   // 64 KB
  float* Ad    = (float*)(ws + 196608);                   // 1 KB
  float* rL    = (float*)(ws + 197632);                   // 1 KB
  float* PWf   = (float*)(ws + 198656);                   // 32 KB
  float* carry = (float*)(ws + 231424);                   // 2 MB
  unsigned int* S = (unsigned int*)(ws + 231424 + 2097152); // 64 MB

  k_prep<<<417, 256, 0, stream>>>(rl, Bc, Cm, W, BdT, CT, Wb, Ad, rL, PWf);
  k_scan<<<BATCH * NCHUNK, 512, 0, stream>>>(x, BdT, Ad, S, carry);
  k_combine<<<BATCH * 32, 256, 0, stream>>>(carry, rL);
  k_apply<<<BATCH * (NCHUNK / NCHK), 512, 0, stream>>>(S, CT, Wb, PWf, Ad, carry,
                                                       lng, lnb, bias, out);
}

// Round 17
// 93.950 us; speedup vs baseline: 1.1969x; 1.0719x over previous
//
#include <hip/hip_runtime.h>

#define BATCH 8
#define CIN 128
#define OCH 128
#define T_LEN 16384
#define NS 256
#define CHUNK 64
#define NCHUNK (T_LEN / CHUNK)   // 256
#define THALF (T_LEN / 2)        // 8192
#define SCHUNK 8192              // u32 per chunk image in global: 32 rows x 256 n
#define HROW 132                 // Hr row stride (u32)
#define NCHK 8                   // chunks per apply block (4 pairs) -> grid 256 = 1 block/CU

typedef __attribute__((ext_vector_type(8))) short bf16x8;
typedef __attribute__((ext_vector_type(4))) float f32x4;
typedef __attribute__((ext_vector_type(4))) unsigned int u32x4;

__device__ __forceinline__ unsigned int pk2(float lo, float hi) {
  unsigned int d;
  asm("v_cvt_pk_bf16_f32 %0, %1, %2" : "=v"(d) : "v"(lo), "v"(hi));
  return d;
}
__device__ __forceinline__ unsigned short f2bf(float f) {
  unsigned int u = __float_as_uint(f);
  u += 0x7fffu + ((u >> 16) & 1u);
  return (unsigned short)(u >> 16);
}
__device__ __forceinline__ float softplusf_(float v) {
  return (v > 20.0f) ? v : log1pf(expf(v));
}
// barrier that does NOT drain vmcnt (keeps global prefetch in flight)
__device__ __forceinline__ void rawbar() {
  __builtin_amdgcn_sched_barrier(0);
  asm volatile("s_waitcnt lgkmcnt(0)" ::: "memory");
  __builtin_amdgcn_sched_barrier(0);
  __builtin_amdgcn_s_barrier();
  __builtin_amdgcn_sched_barrier(0);
}

// ---------------- prep: weights -> bf16, A_d, A_d^L, PWf[tp][n] = A_n^(2tp+1) ----------------
__global__ __launch_bounds__(256) void k_prep(
    const float* __restrict__ rl, const float* __restrict__ Bc,
    const float* __restrict__ Cm, const float* __restrict__ W,
    unsigned short* __restrict__ BdT, unsigned short* __restrict__ CT,
    unsigned short* __restrict__ Wb, float* __restrict__ Ad, float* __restrict__ rL,
    float* __restrict__ PWf)
{
  const int tid = blockIdx.x * 256 + threadIdx.x;
  if (tid < NS * CIN) {                       // BdT[n][c] = B_c[c][n] * (A_d-1)/lam
    const int n = tid >> 7, c = tid & 127;
    float lam = -softplusf_(rl[n]);
    float ad = expf(lam);
    float sc = (ad - 1.0f) / lam;
    BdT[tid] = f2bf(Bc[c * NS + n] * sc);
  } else if (tid < 2 * NS * CIN) {            // CT[o][n] = C[n][o]
    const int i = tid - NS * CIN;
    const int o = i >> 8, n = i & 255;
    CT[i] = f2bf(Cm[n * OCH + o]);
  } else if (tid < 3 * NS * CIN) {            // Wb[o][c2] = W[o][c2]
    const int i = tid - 2 * NS * CIN;
    Wb[i] = f2bf(W[i]);
  } else if (tid < 3 * NS * CIN + NS) {
    const int n = tid - 3 * NS * CIN;
    float lam = -softplusf_(rl[n]);
    Ad[n] = expf(lam);
    rL[n] = expf(lam * (float)CHUNK);
  } else if (tid < 3 * NS * CIN + NS + 32 * NS) {   // PWf[tp][n] = A_n^(2tp+1)
    const int i = tid - (3 * NS * CIN + NS);
    const int tp = i >> 8, n = i & 255;
    float lam = -softplusf_(rl[n]);
    PWf[i] = expf(lam * (float)(2 * tp + 1));
  }
}

// ---------------- chunk-carry combine: Hillis-Steele, 256 blocks (8 n per block) ----------------
__global__ __launch_bounds__(256) void k_combine(float* __restrict__ carry,
                                                 const float* __restrict__ rL)
{
  const int b = blockIdx.x >> 5;
  const int ng = blockIdx.x & 31;     // n-group of 8
  const int t = threadIdx.x;          // chunk index
  __shared__ float Y[8][NCHUNK];
  float* base = carry + ((size_t)b * NCHUNK + t) * NS + ng * 8;
  #pragma unroll
  for (int i4 = 0; i4 < 2; ++i4) {
    float4 q = *(const float4*)(base + i4 * 4);
    Y[i4 * 4 + 0][t] = q.x; Y[i4 * 4 + 1][t] = q.y;
    Y[i4 * 4 + 2][t] = q.z; Y[i4 * 4 + 3][t] = q.w;
  }
  float rp[8];
  #pragma unroll
  for (int i = 0; i < 8; ++i) rp[i] = rL[ng * 8 + i];
  __syncthreads();
  for (int d = 1; d < NCHUNK; d <<= 1) {
    float tmp[8];
    #pragma unroll
    for (int i = 0; i < 8; ++i) tmp[i] = (t >= d) ? Y[i][t - d] : 0.0f;
    __syncthreads();
    #pragma unroll
    for (int i = 0; i < 8; ++i) { Y[i][t] += rp[i] * tmp[i]; rp[i] *= rp[i]; }
    __syncthreads();
  }
  const int tm = (t == 0) ? 0 : (t - 1);
  #pragma unroll
  for (int i4 = 0; i4 < 2; ++i4) {
    float a = Y[i4 * 4 + 0][tm], bb = Y[i4 * 4 + 1][tm];
    float c = Y[i4 * 4 + 2][tm], dd = Y[i4 * 4 + 3][tm];
    float4 q;
    q.x = (t == 0) ? 0.0f : a;  q.y = (t == 0) ? 0.0f : bb;
    q.z = (t == 0) ? 0.0f : c;  q.w = (t == 0) ? 0.0f : dd;
    *(float4*)(base + i4 * 4) = q;
  }
}

// ---------------- k_scan: R13 exact ((512,4), hoisted Bf, pre-barrier constants) ----------------
__global__ __launch_bounds__(512, 4) void k_scan(
    const float* __restrict__ x,
    const unsigned short* __restrict__ BdT,
    const float* __restrict__ Ad,
    unsigned int* __restrict__ s0,
    float* __restrict__ carry)
{
  const int bid = blockIdx.x;
  const int b = bid >> 8;
  const int kc = bid & 255;
  const int tid = threadIdx.x;
  const int w = tid >> 6, l = tid & 63, l15 = l & 15, g = l >> 4;

  __shared__ __align__(16) unsigned int Xt[64 * 64];  // [t][c2 ^ ((t&7)<<2)] packed bf16 pairs

  // ---- stage x: thread -> (c2 = w*8 + (l&7), t-block = (l>>3)*8): contiguous 32B loads ----
  {
    const int c2 = w * 8 + (l & 7);
    const int t0b = (l >> 3) * 8;
    const float* r0 = x + ((size_t)(b * CIN + 2 * c2)) * T_LEN + kc * CHUNK + t0b;
    const f32x4 xa0 = *(const f32x4*)r0;
    const f32x4 xa1 = *(const f32x4*)(r0 + 4);
    const f32x4 xb0 = *(const f32x4*)(r0 + T_LEN);
    const f32x4 xb1 = *(const f32x4*)(r0 + T_LEN + 4);
    #pragma unroll
    for (int k = 0; k < 8; ++k) {
      const int t = t0b + k;
      const float va = (k < 4) ? xa0[k & 3] : xa1[k & 3];
      const float vb = (k < 4) ? xb0[k & 3] : xb1[k & 3];
      Xt[t * 64 + (c2 ^ ((t & 7) << 2))] = pk2(va, vb);
    }
  }

  // ---- per-wave B fragments (n in [32w, 32w+32)) + scan constants (hoisted: loads
  // issue during staging, latency hidden before the barrier) ----
  bf16x8 Bf[2][4];
  #pragma unroll
  for (int nt = 0; nt < 2; ++nt)
    #pragma unroll
    for (int kt = 0; kt < 4; ++kt)
      Bf[nt][kt] = *(const bf16x8*)&BdT[(w * 32 + nt * 16 + l15) * CIN + kt * 32 + g * 8];

  float A1[2], A2[2], A3[2], A4[2], A8[2], A16[2], A4G[2], M1[2], M2[2];
  #pragma unroll
  for (int nt = 0; nt < 2; ++nt) {
    const float a1 = Ad[w * 32 + nt * 16 + l15];
    A1[nt] = a1; A2[nt] = a1 * a1; A3[nt] = A2[nt] * a1; A4[nt] = A2[nt] * A2[nt];
    A8[nt] = A4[nt] * A4[nt]; A16[nt] = A8[nt] * A8[nt];
    float a4g = 1.0f;
    if (g & 1) a4g *= A4[nt];
    if (g & 2) a4g *= A8[nt];
    A4G[nt] = a4g;
    M1[nt] = (g >= 1) ? A4[nt] : 0.0f;
    M2[nt] = (g >= 2) ? A8[nt] : 0.0f;
  }
  __syncthreads();

  // ---- v-GEMM ----
  f32x4 vac[4][2] = {};
  #pragma unroll
  for (int kt = 0; kt < 4; ++kt) {
    bf16x8 afr[4];
    #pragma unroll
    for (int mt = 0; mt < 4; ++mt)
      afr[mt] = *(const bf16x8*)&Xt[(mt * 16 + l15) * 64 + ((kt * 16 + g * 4) ^ ((l15 & 7) << 2))];
    #pragma unroll
    for (int nt = 0; nt < 2; ++nt)
      #pragma unroll
      for (int mt = 0; mt < 4; ++mt)
        vac[mt][nt] = __builtin_amdgcn_mfma_f32_16x16x32_bf16(afr[mt], Bf[nt][kt], vac[mt][nt], 0, 0, 0);
  }

  // ---- in-register scan over t, seed 0 ----
  float crv[2];
  #pragma unroll
  for (int nt = 0; nt < 2; ++nt) {
    float cr = 0.0f;
    #pragma unroll
    for (int mt = 0; mt < 4; ++mt) {
      const float p0 = vac[mt][nt][0];
      const float p1 = fmaf(A1[nt], p0, vac[mt][nt][1]);
      const float p2 = fmaf(A1[nt], p1, vac[mt][nt][2]);
      const float p3 = fmaf(A1[nt], p2, vac[mt][nt][3]);
      float c0 = p3;
      float u = __shfl_up(c0, 16);
      c0 = fmaf(M1[nt], u, c0);
      u = __shfl_up(c0, 32);
      c0 = fmaf(M2[nt], u, c0);
      float e = __shfl_up(c0, 16);
      e = (g == 0) ? 0.0f : e;
      const float seed = fmaf(A4G[nt], cr, e);
      vac[mt][nt][0] = fmaf(A1[nt], seed, p0);
      vac[mt][nt][1] = fmaf(A2[nt], seed, p1);
      vac[mt][nt][2] = fmaf(A3[nt], seed, p2);
      vac[mt][nt][3] = fmaf(A4[nt], seed, p3);
      const float ctop = __shfl(c0, 48 + l15);
      cr = fmaf(A16[nt], cr, ctop);
    }
    crv[nt] = cr;
  }

  // ---- store packed s0 [tp][n] (linear, coalesced) + totals ----
  unsigned int* sc = s0 + (size_t)(b * NCHUNK + kc) * SCHUNK;
  #pragma unroll
  for (int mt = 0; mt < 4; ++mt)
    #pragma unroll
    for (int nt = 0; nt < 2; ++nt) {
      const int n = w * 32 + nt * 16 + l15;
      #pragma unroll
      for (int rp = 0; rp < 2; ++rp) {
        const int tp = mt * 8 + g * 2 + rp;
        sc[tp * 256 + n] = pk2(vac[mt][nt][rp * 2], vac[mt][nt][rp * 2 + 1]);
      }
    }
  if (g == 0) {
    #pragma unroll
    for (int nt = 0; nt < 2; ++nt)
      carry[((size_t)b * NCHUNK + kc) * NS + (w * 32 + nt * 16 + l15)] = crv[nt];
  }
}

// ---------------- k_apply: PAIRED chunks (R13 exact) ----------------
__global__ __launch_bounds__(512, 2) void k_apply(
    const unsigned int* __restrict__ S,
    const unsigned short* __restrict__ CT,
    const unsigned short* __restrict__ Wb,
    const float* __restrict__ PWf,
    const float* __restrict__ Ad,
    const float* __restrict__ carry,
    const float* __restrict__ lng, const float* __restrict__ lnb,
    const float* __restrict__ bias,
    float* __restrict__ out)
{
  const int bid = blockIdx.x;
  const int b = bid / (NCHUNK / NCHK);
  const int kc0 = (bid % (NCHUNK / NCHK)) * NCHK;
  const int tid = threadIdx.x;
  const int w = tid >> 6, l = tid & 63, l15 = l & 15, g = l >> 4;
  const int tt = w >> 2, oq = w & 3;

  __shared__ __align__(16) unsigned short V2a[64 * 256];  // 32 KB, swizzled bf16 [t][n]
  __shared__ __align__(16) unsigned short V2b[64 * 256];  // 32 KB
  __shared__ __align__(16) unsigned int Hra[32 * HROW];   // 16.9 KB
  __shared__ __align__(16) unsigned int Hrb[32 * HROW];   // 16.9 KB
  __shared__ __align__(16) float Lexf[2][64 * 8];         // 4 KB

  const f32x4 adv = *(const f32x4*)&Ad[4 * l];

  // ---- loop-invariant fragments in registers (loaded ONCE per block, amortized over 8 chunks) ----
  bf16x8 ctf[8][2];
  #pragma unroll
  for (int kt = 0; kt < 8; ++kt)
    #pragma unroll
    for (int ot = 0; ot < 2; ++ot)
      ctf[kt][ot] = *(const bf16x8*)&CT[(oq * 32 + ot * 16 + l15) * NS + kt * 32 + g * 8];
  bf16x8 wf[8];
  #pragma unroll
  for (int kt = 0; kt < 8; ++kt)
    wf[kt] = *(const bf16x8*)&Wb[(w * 16 + l15) * NS + kt * 32 + g * 8];
  f32x4 pwv[4];
  #pragma unroll
  for (int r = 0; r < 4; ++r)
    pwv[r] = *(const f32x4*)&PWf[(r * 8 + w) * 256 + 4 * l];
  const float ga0 = lng[oq * 32 + l15],      be0 = lnb[oq * 32 + l15];
  const float ga1 = lng[oq * 32 + 16 + l15], be1 = lnb[oq * 32 + 16 + l15];
  const float bia = bias[w * 16 + l15];

  u32x4 sa0, sa1, sa2, sa3, sb0, sb1, sb2, sb3;
  f32x4 sda, sdb;

#define LOAD_ST(KC, T0, T1, T2, T3, SD) do {                                \
    const unsigned int* scb_ = S + (size_t)(b * NCHUNK + (KC)) * SCHUNK;    \
    T0 = *(const u32x4*)&scb_[0 * 2048 + tid * 4];                          \
    T1 = *(const u32x4*)&scb_[1 * 2048 + tid * 4];                          \
    T2 = *(const u32x4*)&scb_[2 * 2048 + tid * 4];                          \
    T3 = *(const u32x4*)&scb_[3 * 2048 + tid * 4];                          \
    SD = *(const f32x4*)&carry[((size_t)b * NCHUNK + (KC)) * NS + 4 * l];   \
  } while (0)

  // thread owns t-pair rows tp = RR*8+w, cols n = 4l..4l+3; writes rows 2tp (lo) and 2tp+1 (hi)
#define CORRECT_ROW(DSTV, QV, RR, SD) do {                                  \
    const float e00 = SD[0] * pwv[RR][0];                                   \
    const float e01 = SD[1] * pwv[RR][1];                                   \
    const float e02 = SD[2] * pwv[RR][2];                                   \
    const float e03 = SD[3] * pwv[RR][3];                                   \
    const float lo0 = __uint_as_float(QV[0] << 16) + e00;                   \
    const float hi0 = __uint_as_float(QV[0] & 0xffff0000u) + e00 * adv[0];  \
    const float lo1 = __uint_as_float(QV[1] << 16) + e01;                   \
    const float hi1 = __uint_as_float(QV[1] & 0xffff0000u) + e01 * adv[1];  \
    const float lo2 = __uint_as_float(QV[2] << 16) + e02;                   \
    const float hi2 = __uint_as_float(QV[2] & 0xffff0000u) + e02 * adv[2];  \
    const float lo3 = __uint_as_float(QV[3] << 16) + e03;                   \
    const float hi3 = __uint_as_float(QV[3] & 0xffff0000u) + e03 * adv[3];  \
    const int t0_ = ((RR) * 8 + w) * 2;                                     \
    const int t1_ = t0_ + 1;                                                \
    uint2 wlo; wlo.x = pk2(lo0, lo1); wlo.y = pk2(lo2, lo3);                \
    uint2 whi; whi.x = pk2(hi0, hi1); whi.y = pk2(hi2, hi3);                \
    *(uint2*)&DSTV[t0_ * 256 + ((((l >> 1) ^ ((t0_ & 7) << 2)) << 3) | ((l & 1) << 2))] = wlo; \
    *(uint2*)&DSTV[t1_ * 256 + ((((l >> 1) ^ ((t1_ & 7) << 2)) << 3) | ((l & 1) << 2))] = whi; \
  } while (0)

#define CORRECT_STORE(DSTV, T0, T1, T2, T3, SD) do {                        \
    CORRECT_ROW(DSTV, T0, 0, SD);                                           \
    CORRECT_ROW(DSTV, T1, 1, SD);                                           \
    CORRECT_ROW(DSTV, T2, 2, SD);                                           \
    CORRECT_ROW(DSTV, T3, 3, SD);                                           \
  } while (0)

  // y-GEMM over one V2 buffer -> yac + LN partials into Lexf[IDX]
#define YGEMM(V2X, YAC, IDX) do {                                           \
    _Pragma("unroll")                                                       \
    for (int kt = 0; kt < 8; ++kt) {                                        \
      bf16x8 As0, As1;                                                      \
      {                                                                     \
        const int t0 = tt * 32 + l15;                                       \
        As0 = *(const bf16x8*)&V2X[t0 * 256 + (((kt * 4 + g) ^ ((t0 & 7) << 2)) << 3)]; \
        const int t1 = tt * 32 + 16 + l15;                                  \
        As1 = *(const bf16x8*)&V2X[t1 * 256 + (((kt * 4 + g) ^ ((t1 & 7) << 2)) << 3)]; \
      }                                                                     \
      _Pragma("unroll")                                                     \
      for (int ot = 0; ot < 2; ++ot) {                                      \
        YAC[0][ot] = __builtin_amdgcn_mfma_f32_16x16x32_bf16(As0, ctf[kt][ot], YAC[0][ot], 0, 0, 0); \
        YAC[1][ot] = __builtin_amdgcn_mfma_f32_16x16x32_bf16(As1, ctf[kt][ot], YAC[1][ot], 0, 0, 0); \
      }                                                                     \
    }                                                                       \
    _Pragma("unroll")                                                       \
    for (int mt = 0; mt < 2; ++mt)                                          \
      _Pragma("unroll")                                                     \
      for (int r = 0; r < 4; ++r) {                                         \
        float s1 = YAC[mt][0][r] + YAC[mt][1][r];                           \
        float s2 = YAC[mt][0][r] * YAC[mt][0][r] + YAC[mt][1][r] * YAC[mt][1][r]; \
        _Pragma("unroll")                                                   \
        for (int d = 1; d < 16; d <<= 1) { s1 += __shfl_xor(s1, d); s2 += __shfl_xor(s2, d); } \
        if (l15 == 0) {                                                     \
          const int t = tt * 32 + mt * 16 + g * 4 + r;                      \
          *(float2*)&Lexf[IDX][t * 8 + oq * 2] = make_float2(s1, s2);       \
        }                                                                   \
      }                                                                     \
  } while (0)

  // LN finish + SiLU from YAC -> HRX
#define LNSILU(HRX, YAC, IDX) do {                                          \
    _Pragma("unroll")                                                       \
    for (int mt = 0; mt < 2; ++mt) {                                        \
      float mu[4], rs[4];                                                   \
      _Pragma("unroll")                                                     \
      for (int r = 0; r < 4; ++r) {                                         \
        const int t = tt * 32 + mt * 16 + g * 4 + r;                        \
        const float4 f0 = *(const float4*)&Lexf[IDX][t * 8];                \
        const float4 f1 = *(const float4*)&Lexf[IDX][t * 8 + 4];            \
        const float m = (f0.x + f0.z + f1.x + f1.z) * (1.0f / 128.0f);      \
        const float va = (f0.y + f0.w + f1.y + f1.w) * (1.0f / 128.0f) - m * m; \
        mu[r] = m;                                                          \
        rs[r] = rsqrtf(va + 1e-5f);                                         \
      }                                                                     \
      _Pragma("unroll")                                                     \
      for (int ot = 0; ot < 2; ++ot) {                                      \
        const int o = oq * 32 + ot * 16 + l15;                              \
        const float ga = ot ? ga1 : ga0;                                    \
        const float be = ot ? be1 : be0;                                    \
        _Pragma("unroll")                                                   \
        for (int rp = 0; rp < 2; ++rp) {                                    \
          float h0 = (YAC[mt][ot][rp * 2] - mu[rp * 2]) * rs[rp * 2] * ga + be; \
          h0 = h0 * __builtin_amdgcn_rcpf(1.0f + __expf(-h0));              \
          float h1 = (YAC[mt][ot][rp * 2 + 1] - mu[rp * 2 + 1]) * rs[rp * 2 + 1] * ga + be; \
          h1 = h1 * __builtin_amdgcn_rcpf(1.0f + __expf(-h1));              \
          const int t2 = tt * 16 + mt * 8 + g * 2 + rp;                     \
          HRX[t2 * HROW + o] = pk2(h0, h1);                                 \
        }                                                                   \
      }                                                                     \
    }                                                                       \
  } while (0)

  // out-GEMM from HRX -> global at chunk KC
#define OUTGEMM(HRX, KC) do {                                               \
    f32x4 oac0 = {}, oac1 = {};                                             \
    _Pragma("unroll")                                                       \
    for (int kt = 0; kt < 8; ++kt) {                                        \
      bf16x8 Aa0, Aa1;                                                      \
      {                                                                     \
        union { bf16x8 v; u32x4 u; } Ax;                                    \
        Ax.u = *(const u32x4*)&HRX[(l15) * HROW + kt * 16 + g * 4];         \
        Aa0 = Ax.v;                                                         \
        Ax.u = *(const u32x4*)&HRX[(16 + l15) * HROW + kt * 16 + g * 4];    \
        Aa1 = Ax.v;                                                         \
      }                                                                     \
      oac0 = __builtin_amdgcn_mfma_f32_16x16x32_bf16(Aa0, wf[kt], oac0, 0, 0, 0); \
      oac1 = __builtin_amdgcn_mfma_f32_16x16x32_bf16(Aa1, wf[kt], oac1, 0, 0, 0); \
    }                                                                       \
    const int o = w * 16 + l15;                                             \
    float4 q0;                                                              \
    q0.x = oac0[0] + bia; q0.y = oac0[1] + bia;                             \
    q0.z = oac0[2] + bia; q0.w = oac0[3] + bia;                             \
    *(float4*)(out + ((size_t)(b * OCH + o)) * THALF + (KC) * 32 + g * 4) = q0; \
    float4 q1;                                                              \
    q1.x = oac1[0] + bia; q1.y = oac1[1] + bia;                             \
    q1.z = oac1[2] + bia; q1.w = oac1[3] + bia;                             \
    *(float4*)(out + ((size_t)(b * OCH + o)) * THALF + (KC) * 32 + 16 + g * 4) = q1; \
  } while (0)

  // ---- prologue: pair 0 -> V2a/V2b; prefetch pair 1 into registers ----
  LOAD_ST(kc0 + 0, sa0, sa1, sa2, sa3, sda);
  CORRECT_STORE(V2a, sa0, sa1, sa2, sa3, sda);
  LOAD_ST(kc0 + 1, sb0, sb1, sb2, sb3, sdb);
  CORRECT_STORE(V2b, sb0, sb1, sb2, sb3, sdb);
  LOAD_ST(kc0 + 2, sa0, sa1, sa2, sa3, sda);
  LOAD_ST(kc0 + 3, sb0, sb1, sb2, sb3, sdb);
  rawbar();

  #pragma unroll 1
  for (int i = 0; i < NCHK / 2; ++i) {
    const int kcA = kc0 + 2 * i;
    const int kcB = kcA + 1;

    // ---- B: two independent y-GEMMs + LN partials ----
    f32x4 yacA[2][2] = {};
    f32x4 yacB[2][2] = {};
    YGEMM(V2a, yacA, 0);
    YGEMM(V2b, yacB, 1);
    rawbar();   // C: Lex visible; V2a/V2b fully read

    // ---- D: LN/SiLU both chunks; stage next pair into V2; prefetch pair i+2 ----
    LNSILU(Hra, yacA, 0);
    LNSILU(Hrb, yacB, 1);
    if (i + 1 < NCHK / 2) {
      CORRECT_STORE(V2a, sa0, sa1, sa2, sa3, sda);
      CORRECT_STORE(V2b, sb0, sb1, sb2, sb3, sdb);
      if (i + 2 < NCHK / 2) {
        LOAD_ST(kcA + 4, sa0, sa1, sa2, sa3, sda);
        LOAD_ST(kcB + 4, sb0, sb1, sb2, sb3, sdb);
      }
    }
    rawbar();   // E: Hr + next-pair V2 visible

    // ---- F: two independent out-GEMMs -> direct stores ----
    OUTGEMM(Hra, kcA);
    OUTGEMM(Hrb, kcB);
  }
#undef LOAD_ST
#undef CORRECT_ROW
#undef CORRECT_STORE
#undef YGEMM
#undef LNSILU
#undef OUTGEMM
}

// ---------------- launch ----------------
extern "C" void kernel_launch(void* const* d_in, const int* in_sizes, int n_in,
                              void* d_out, int out_size, void* d_ws, size_t ws_size,
                              hipStream_t stream) {
  const float* x    = (const float*)d_in[0];
  const float* rl   = (const float*)d_in[1];
  const float* Bc   = (const float*)d_in[2];
  const float* Cm   = (const float*)d_in[3];
  const float* lng  = (const float*)d_in[4];
  const float* lnb  = (const float*)d_in[5];
  const float* W    = (const float*)d_in[6];
  const float* bias = (const float*)d_in[7];
  float* out = (float*)d_out;

  char* ws = (char*)d_ws;
  unsigned short* BdT = (unsigned short*)(ws);            // 64 KB
  unsigned short* CT  = (unsigned short*)(ws + 65536);    // 64 KB
  unsigned short* Wb  = (unsigned short*)(ws + 131072);   // 64 KB
  float* Ad    = (float*)(ws + 196608);                   // 1 KB
  float* rL    = (float*)(ws + 197632);                   // 1 KB
  float* PWf   = (float*)(ws + 198656);                   // 32 KB
  float* carry = (float*)(ws + 231424);                   // 2 MB
  unsigned int* S = (unsigned int*)(ws + 231424 + 2097152); // 64 MB

  k_prep<<<417, 256, 0, stream>>>(rl, Bc, Cm, W, BdT, CT, Wb, Ad, rL, PWf);
  k_scan<<<BATCH * NCHUNK, 512, 0, stream>>>(x, BdT, Ad, S, carry);
  k_combine<<<BATCH * 32, 256, 0, stream>>>(carry, rL);
  k_apply<<<BATCH * (NCHUNK / NCHK), 512, 0, stream>>>(S, CT, Wb, PWf, Ad, carry,
                                                       lng, lnb, bias, out);
}

// Round 18
// 91.945 us; speedup vs baseline: 1.2230x; 1.0218x over previous
//
#include <hip/hip_runtime.h>

#define BATCH 8
#define CIN 128
#define OCH 128
#define T_LEN 16384
#define NS 256
#define CHUNK 64
#define NCHUNK (T_LEN / CHUNK)   // 256
#define THALF (T_LEN / 2)        // 8192
#define SCHUNK 8192              // u32 per chunk image in global: 32 rows x 256 n
#define HROW 132                 // Hr row stride (u32)
#define NCHK 8                   // chunks per apply block (4 pairs) -> grid 256 = 1 block/CU
#define SCHK 4                   // chunks per scan block -> grid 512 = 2 blocks/CU

typedef __attribute__((ext_vector_type(8))) short bf16x8;
typedef __attribute__((ext_vector_type(4))) float f32x4;
typedef __attribute__((ext_vector_type(4))) unsigned int u32x4;

__device__ __forceinline__ unsigned int pk2(float lo, float hi) {
  unsigned int d;
  asm("v_cvt_pk_bf16_f32 %0, %1, %2" : "=v"(d) : "v"(lo), "v"(hi));
  return d;
}
__device__ __forceinline__ unsigned short f2bf(float f) {
  unsigned int u = __float_as_uint(f);
  u += 0x7fffu + ((u >> 16) & 1u);
  return (unsigned short)(u >> 16);
}
__device__ __forceinline__ float softplusf_(float v) {
  return (v > 20.0f) ? v : log1pf(expf(v));
}
// barrier that does NOT drain vmcnt (keeps global prefetch in flight)
__device__ __forceinline__ void rawbar() {
  __builtin_amdgcn_sched_barrier(0);
  asm volatile("s_waitcnt lgkmcnt(0)" ::: "memory");
  __builtin_amdgcn_sched_barrier(0);
  __builtin_amdgcn_s_barrier();
  __builtin_amdgcn_sched_barrier(0);
}

// ---------------- prep: weights -> bf16, A_d, A_d^L, PWf[tp][n] = A_n^(2tp+1) ----------------
__global__ __launch_bounds__(256) void k_prep(
    const float* __restrict__ rl, const float* __restrict__ Bc,
    const float* __restrict__ Cm, const float* __restrict__ W,
    unsigned short* __restrict__ BdT, unsigned short* __restrict__ CT,
    unsigned short* __restrict__ Wb, float* __restrict__ Ad, float* __restrict__ rL,
    float* __restrict__ PWf)
{
  const int tid = blockIdx.x * 256 + threadIdx.x;
  if (tid < NS * CIN) {                       // BdT[n][c] = B_c[c][n] * (A_d-1)/lam
    const int n = tid >> 7, c = tid & 127;
    float lam = -softplusf_(rl[n]);
    float ad = expf(lam);
    float sc = (ad - 1.0f) / lam;
    BdT[tid] = f2bf(Bc[c * NS + n] * sc);
  } else if (tid < 2 * NS * CIN) {            // CT[o][n] = C[n][o]
    const int i = tid - NS * CIN;
    const int o = i >> 8, n = i & 255;
    CT[i] = f2bf(Cm[n * OCH + o]);
  } else if (tid < 3 * NS * CIN) {            // Wb[o][c2] = W[o][c2]
    const int i = tid - 2 * NS * CIN;
    Wb[i] = f2bf(W[i]);
  } else if (tid < 3 * NS * CIN + NS) {
    const int n = tid - 3 * NS * CIN;
    float lam = -softplusf_(rl[n]);
    Ad[n] = expf(lam);
    rL[n] = expf(lam * (float)CHUNK);
  } else if (tid < 3 * NS * CIN + NS + 32 * NS) {   // PWf[tp][n] = A_n^(2tp+1)
    const int i = tid - (3 * NS * CIN + NS);
    const int tp = i >> 8, n = i & 255;
    float lam = -softplusf_(rl[n]);
    PWf[i] = expf(lam * (float)(2 * tp + 1));
  }
}

// ---------------- chunk-carry combine: Hillis-Steele, 256 blocks (8 n per block) ----------------
__global__ __launch_bounds__(256) void k_combine(float* __restrict__ carry,
                                                 const float* __restrict__ rL)
{
  const int b = blockIdx.x >> 5;
  const int ng = blockIdx.x & 31;     // n-group of 8
  const int t = threadIdx.x;          // chunk index
  __shared__ float Y[8][NCHUNK];
  float* base = carry + ((size_t)b * NCHUNK + t) * NS + ng * 8;
  #pragma unroll
  for (int i4 = 0; i4 < 2; ++i4) {
    float4 q = *(const float4*)(base + i4 * 4);
    Y[i4 * 4 + 0][t] = q.x; Y[i4 * 4 + 1][t] = q.y;
    Y[i4 * 4 + 2][t] = q.z; Y[i4 * 4 + 3][t] = q.w;
  }
  float rp[8];
  #pragma unroll
  for (int i = 0; i < 8; ++i) rp[i] = rL[ng * 8 + i];
  __syncthreads();
  for (int d = 1; d < NCHUNK; d <<= 1) {
    float tmp[8];
    #pragma unroll
    for (int i = 0; i < 8; ++i) tmp[i] = (t >= d) ? Y[i][t - d] : 0.0f;
    __syncthreads();
    #pragma unroll
    for (int i = 0; i < 8; ++i) { Y[i][t] += rp[i] * tmp[i]; rp[i] *= rp[i]; }
    __syncthreads();
  }
  const int tm = (t == 0) ? 0 : (t - 1);
  #pragma unroll
  for (int i4 = 0; i4 < 2; ++i4) {
    float a = Y[i4 * 4 + 0][tm], bb = Y[i4 * 4 + 1][tm];
    float c = Y[i4 * 4 + 2][tm], dd = Y[i4 * 4 + 3][tm];
    float4 q;
    q.x = (t == 0) ? 0.0f : a;  q.y = (t == 0) ? 0.0f : bb;
    q.z = (t == 0) ? 0.0f : c;  q.w = (t == 0) ? 0.0f : dd;
    *(float4*)(base + i4 * 4) = q;
  }
}

// ---------------- k_scan: persistent 4-chunk blocks, prefetch-pipelined ----------------
// R18: 2048 cold-start blocks -> 512 blocks x 4 chunks (2/CU, independent barriers).
// Double-buffered Xt; next chunk's 16 x-loads issued right after the barrier and left
// in flight across GEMM+scan+store (T14). One barrier per chunk. (512,3) -> ~85-reg cap,
// peak live ~75 (Bf 16 + consts 18 + x-staging 16 + vac 16 + afr 8) -> no spill.
__global__ __launch_bounds__(512, 3) void k_scan(
    const float* __restrict__ x,
    const unsigned short* __restrict__ BdT,
    const float* __restrict__ Ad,
    unsigned int* __restrict__ s0,
    float* __restrict__ carry)
{
  const int bid = blockIdx.x;
  const int b = bid / (NCHUNK / SCHK);
  const int kc0 = (bid % (NCHUNK / SCHK)) * SCHK;
  const int tid = threadIdx.x;
  const int w = tid >> 6, l = tid & 63, l15 = l & 15, g = l >> 4;

  __shared__ __align__(16) unsigned int Xt[2][64 * 64];  // 2 x 16 KB, swizzled bf16 pairs

  // ---- per-wave B fragments + scan constants (hoisted; amortized over 4 chunks) ----
  bf16x8 Bf[2][4];
  #pragma unroll
  for (int nt = 0; nt < 2; ++nt)
    #pragma unroll
    for (int kt = 0; kt < 4; ++kt)
      Bf[nt][kt] = *(const bf16x8*)&BdT[(w * 32 + nt * 16 + l15) * CIN + kt * 32 + g * 8];

  float A1[2], A2[2], A3[2], A4[2], A8[2], A16[2], A4G[2], M1[2], M2[2];
  #pragma unroll
  for (int nt = 0; nt < 2; ++nt) {
    const float a1 = Ad[w * 32 + nt * 16 + l15];
    A1[nt] = a1; A2[nt] = a1 * a1; A3[nt] = A2[nt] * a1; A4[nt] = A2[nt] * A2[nt];
    A8[nt] = A4[nt] * A4[nt]; A16[nt] = A8[nt] * A8[nt];
    float a4g = 1.0f;
    if (g & 1) a4g *= A4[nt];
    if (g & 2) a4g *= A8[nt];
    A4G[nt] = a4g;
    M1[nt] = (g >= 1) ? A4[nt] : 0.0f;
    M2[nt] = (g >= 2) ? A8[nt] : 0.0f;
  }

  // ---- x addressing: thread -> (c2 = w*8 + (l&7), t-block = (l>>3)*8); 32B rows ----
  const int c2 = w * 8 + (l & 7);
  const int t0b = (l >> 3) * 8;
  const float* xbase = x + ((size_t)(b * CIN + 2 * c2)) * T_LEN + t0b;

  // ---- prologue: load chunk kc0 into registers ----
  f32x4 xa0, xa1, xb0, xb1;
  {
    const float* r0 = xbase + kc0 * CHUNK;
    xa0 = *(const f32x4*)r0;
    xa1 = *(const f32x4*)(r0 + 4);
    xb0 = *(const f32x4*)(r0 + T_LEN);
    xb1 = *(const f32x4*)(r0 + T_LEN + 4);
  }

  int cur = 0;
  #pragma unroll 1
  for (int i = 0; i < SCHK; ++i) {
    const int kc = kc0 + i;

    // ---- stage staged-registers -> Xt[cur] ----
    #pragma unroll
    for (int k = 0; k < 8; ++k) {
      const int t = t0b + k;
      const float va = (k < 4) ? xa0[k & 3] : xa1[k & 3];
      const float vb = (k < 4) ? xb0[k & 3] : xb1[k & 3];
      Xt[cur][t * 64 + (c2 ^ ((t & 7) << 2))] = pk2(va, vb);
    }
    rawbar();   // all waves staged; vmcnt NOT drained

    // ---- issue next chunk's x loads (in flight across GEMM+scan+store) ----
    if (i + 1 < SCHK) {
      const float* r0 = xbase + (kc + 1) * CHUNK;
      xa0 = *(const f32x4*)r0;
      xa1 = *(const f32x4*)(r0 + 4);
      xb0 = *(const f32x4*)(r0 + T_LEN);
      xb1 = *(const f32x4*)(r0 + T_LEN + 4);
    }

    // ---- v-GEMM on Xt[cur] ----
    f32x4 vac[4][2] = {};
    #pragma unroll
    for (int kt = 0; kt < 4; ++kt) {
      bf16x8 afr[4];
      #pragma unroll
      for (int mt = 0; mt < 4; ++mt)
        afr[mt] = *(const bf16x8*)&Xt[cur][(mt * 16 + l15) * 64 + ((kt * 16 + g * 4) ^ ((l15 & 7) << 2))];
      #pragma unroll
      for (int nt = 0; nt < 2; ++nt)
        #pragma unroll
        for (int mt = 0; mt < 4; ++mt)
          vac[mt][nt] = __builtin_amdgcn_mfma_f32_16x16x32_bf16(afr[mt], Bf[nt][kt], vac[mt][nt], 0, 0, 0);
    }

    // ---- in-register scan over t, seed 0 ----
    float crv[2];
    #pragma unroll
    for (int nt = 0; nt < 2; ++nt) {
      float cr = 0.0f;
      #pragma unroll
      for (int mt = 0; mt < 4; ++mt) {
        const float p0 = vac[mt][nt][0];
        const float p1 = fmaf(A1[nt], p0, vac[mt][nt][1]);
        const float p2 = fmaf(A1[nt], p1, vac[mt][nt][2]);
        const float p3 = fmaf(A1[nt], p2, vac[mt][nt][3]);
        float c0 = p3;
        float u = __shfl_up(c0, 16);
        c0 = fmaf(M1[nt], u, c0);
        u = __shfl_up(c0, 32);
        c0 = fmaf(M2[nt], u, c0);
        float e = __shfl_up(c0, 16);
        e = (g == 0) ? 0.0f : e;
        const float seed = fmaf(A4G[nt], cr, e);
        vac[mt][nt][0] = fmaf(A1[nt], seed, p0);
        vac[mt][nt][1] = fmaf(A2[nt], seed, p1);
        vac[mt][nt][2] = fmaf(A3[nt], seed, p2);
        vac[mt][nt][3] = fmaf(A4[nt], seed, p3);
        const float ctop = __shfl(c0, 48 + l15);
        cr = fmaf(A16[nt], cr, ctop);
      }
      crv[nt] = cr;
    }

    // ---- store packed s0 [tp][n] (linear, coalesced) + totals ----
    unsigned int* sc = s0 + (size_t)(b * NCHUNK + kc) * SCHUNK;
    #pragma unroll
    for (int mt = 0; mt < 4; ++mt)
      #pragma unroll
      for (int nt = 0; nt < 2; ++nt) {
        const int n = w * 32 + nt * 16 + l15;
        #pragma unroll
        for (int rp = 0; rp < 2; ++rp) {
          const int tp = mt * 8 + g * 2 + rp;
          sc[tp * 256 + n] = pk2(vac[mt][nt][rp * 2], vac[mt][nt][rp * 2 + 1]);
        }
      }
    if (g == 0) {
      #pragma unroll
      for (int nt = 0; nt < 2; ++nt)
        carry[((size_t)b * NCHUNK + kc) * NS + (w * 32 + nt * 16 + l15)] = crv[nt];
    }
    cur ^= 1;
  }
}

// ---------------- k_apply: PAIRED chunks (R13/R17 exact) ----------------
__global__ __launch_bounds__(512, 2) void k_apply(
    const unsigned int* __restrict__ S,
    const unsigned short* __restrict__ CT,
    const unsigned short* __restrict__ Wb,
    const float* __restrict__ PWf,
    const float* __restrict__ Ad,
    const float* __restrict__ carry,
    const float* __restrict__ lng, const float* __restrict__ lnb,
    const float* __restrict__ bias,
    float* __restrict__ out)
{
  const int bid = blockIdx.x;
  const int b = bid / (NCHUNK / NCHK);
  const int kc0 = (bid % (NCHUNK / NCHK)) * NCHK;
  const int tid = threadIdx.x;
  const int w = tid >> 6, l = tid & 63, l15 = l & 15, g = l >> 4;
  const int tt = w >> 2, oq = w & 3;

  __shared__ __align__(16) unsigned short V2a[64 * 256];  // 32 KB, swizzled bf16 [t][n]
  __shared__ __align__(16) unsigned short V2b[64 * 256];  // 32 KB
  __shared__ __align__(16) unsigned int Hra[32 * HROW];   // 16.9 KB
  __shared__ __align__(16) unsigned int Hrb[32 * HROW];   // 16.9 KB
  __shared__ __align__(16) float Lexf[2][64 * 8];         // 4 KB

  const f32x4 adv = *(const f32x4*)&Ad[4 * l];

  // ---- loop-invariant fragments in registers (loaded ONCE per block, amortized over 8 chunks) ----
  bf16x8 ctf[8][2];
  #pragma unroll
  for (int kt = 0; kt < 8; ++kt)
    #pragma unroll
    for (int ot = 0; ot < 2; ++ot)
      ctf[kt][ot] = *(const bf16x8*)&CT[(oq * 32 + ot * 16 + l15) * NS + kt * 32 + g * 8];
  bf16x8 wf[8];
  #pragma unroll
  for (int kt = 0; kt < 8; ++kt)
    wf[kt] = *(const bf16x8*)&Wb[(w * 16 + l15) * NS + kt * 32 + g * 8];
  f32x4 pwv[4];
  #pragma unroll
  for (int r = 0; r < 4; ++r)
    pwv[r] = *(const f32x4*)&PWf[(r * 8 + w) * 256 + 4 * l];
  const float ga0 = lng[oq * 32 + l15],      be0 = lnb[oq * 32 + l15];
  const float ga1 = lng[oq * 32 + 16 + l15], be1 = lnb[oq * 32 + 16 + l15];
  const float bia = bias[w * 16 + l15];

  u32x4 sa0, sa1, sa2, sa3, sb0, sb1, sb2, sb3;
  f32x4 sda, sdb;

#define LOAD_ST(KC, T0, T1, T2, T3, SD) do {                                \
    const unsigned int* scb_ = S + (size_t)(b * NCHUNK + (KC)) * SCHUNK;    \
    T0 = *(const u32x4*)&scb_[0 * 2048 + tid * 4];                          \
    T1 = *(const u32x4*)&scb_[1 * 2048 + tid * 4];                          \
    T2 = *(const u32x4*)&scb_[2 * 2048 + tid * 4];                          \
    T3 = *(const u32x4*)&scb_[3 * 2048 + tid * 4];                          \
    SD = *(const f32x4*)&carry[((size_t)b * NCHUNK + (KC)) * NS + 4 * l];   \
  } while (0)

  // thread owns t-pair rows tp = RR*8+w, cols n = 4l..4l+3; writes rows 2tp (lo) and 2tp+1 (hi)
#define CORRECT_ROW(DSTV, QV, RR, SD) do {                                  \
    const float e00 = SD[0] * pwv[RR][0];                                   \
    const float e01 = SD[1] * pwv[RR][1];                                   \
    const float e02 = SD[2] * pwv[RR][2];                                   \
    const float e03 = SD[3] * pwv[RR][3];                                   \
    const float lo0 = __uint_as_float(QV[0] << 16) + e00;                   \
    const float hi0 = __uint_as_float(QV[0] & 0xffff0000u) + e00 * adv[0];  \
    const float lo1 = __uint_as_float(QV[1] << 16) + e01;                   \
    const float hi1 = __uint_as_float(QV[1] & 0xffff0000u) + e01 * adv[1];  \
    const float lo2 = __uint_as_float(QV[2] << 16) + e02;                   \
    const float hi2 = __uint_as_float(QV[2] & 0xffff0000u) + e02 * adv[2];  \
    const float lo3 = __uint_as_float(QV[3] << 16) + e03;                   \
    const float hi3 = __uint_as_float(QV[3] & 0xffff0000u) + e03 * adv[3];  \
    const int t0_ = ((RR) * 8 + w) * 2;                                     \
    const int t1_ = t0_ + 1;                                                \
    uint2 wlo; wlo.x = pk2(lo0, lo1); wlo.y = pk2(lo2, lo3);                \
    uint2 whi; whi.x = pk2(hi0, hi1); whi.y = pk2(hi2, hi3);                \
    *(uint2*)&DSTV[t0_ * 256 + ((((l >> 1) ^ ((t0_ & 7) << 2)) << 3) | ((l & 1) << 2))] = wlo; \
    *(uint2*)&DSTV[t1_ * 256 + ((((l >> 1) ^ ((t1_ & 7) << 2)) << 3) | ((l & 1) << 2))] = whi; \
  } while (0)

#define CORRECT_STORE(DSTV, T0, T1, T2, T3, SD) do {                        \
    CORRECT_ROW(DSTV, T0, 0, SD);                                           \
    CORRECT_ROW(DSTV, T1, 1, SD);                                           \
    CORRECT_ROW(DSTV, T2, 2, SD);                                           \
    CORRECT_ROW(DSTV, T3, 3, SD);                                           \
  } while (0)

  // y-GEMM over one V2 buffer -> yac + LN partials into Lexf[IDX]
#define YGEMM(V2X, YAC, IDX) do {                                           \
    _Pragma("unroll")                                                       \
    for (int kt = 0; kt < 8; ++kt) {                                        \
      bf16x8 As0, As1;                                                      \
      {                                                                     \
        const int t0 = tt * 32 + l15;                                       \
        As0 = *(const bf16x8*)&V2X[t0 * 256 + (((kt * 4 + g) ^ ((t0 & 7) << 2)) << 3)]; \
        const int t1 = tt * 32 + 16 + l15;                                  \
        As1 = *(const bf16x8*)&V2X[t1 * 256 + (((kt * 4 + g) ^ ((t1 & 7) << 2)) << 3)]; \
      }                                                                     \
      _Pragma("unroll")                                                     \
      for (int ot = 0; ot < 2; ++ot) {                                      \
        YAC[0][ot] = __builtin_amdgcn_mfma_f32_16x16x32_bf16(As0, ctf[kt][ot], YAC[0][ot], 0, 0, 0); \
        YAC[1][ot] = __builtin_amdgcn_mfma_f32_16x16x32_bf16(As1, ctf[kt][ot], YAC[1][ot], 0, 0, 0); \
      }                                                                     \
    }                                                                       \
    _Pragma("unroll")                                                       \
    for (int mt = 0; mt < 2; ++mt)                                          \
      _Pragma("unroll")                                                     \
      for (int r = 0; r < 4; ++r) {                                         \
        float s1 = YAC[mt][0][r] + YAC[mt][1][r];                           \
        float s2 = YAC[mt][0][r] * YAC[mt][0][r] + YAC[mt][1][r] * YAC[mt][1][r]; \
        _Pragma("unroll")                                                   \
        for (int d = 1; d < 16; d <<= 1) { s1 += __shfl_xor(s1, d); s2 += __shfl_xor(s2, d); } \
        if (l15 == 0) {                                                     \
          const int t = tt * 32 + mt * 16 + g * 4 + r;                      \
          *(float2*)&Lexf[IDX][t * 8 + oq * 2] = make_float2(s1, s2);       \
        }                                                                   \
      }                                                                     \
  } while (0)

  // LN finish + SiLU from YAC -> HRX
#define LNSILU(HRX, YAC, IDX) do {                                          \
    _Pragma("unroll")                                                       \
    for (int mt = 0; mt < 2; ++mt) {                                        \
      float mu[4], rs[4];                                                   \
      _Pragma("unroll")                                                     \
      for (int r = 0; r < 4; ++r) {                                         \
        const int t = tt * 32 + mt * 16 + g * 4 + r;                        \
        const float4 f0 = *(const float4*)&Lexf[IDX][t * 8];                \
        const float4 f1 = *(const float4*)&Lexf[IDX][t * 8 + 4];            \
        const float m = (f0.x + f0.z + f1.x + f1.z) * (1.0f / 128.0f);      \
        const float va = (f0.y + f0.w + f1.y + f1.w) * (1.0f / 128.0f) - m * m; \
        mu[r] = m;                                                          \
        rs[r] = rsqrtf(va + 1e-5f);                                         \
      }                                                                     \
      _Pragma("unroll")                                                     \
      for (int ot = 0; ot < 2; ++ot) {                                      \
        const int o = oq * 32 + ot * 16 + l15;                              \
        const float ga = ot ? ga1 : ga0;                                    \
        const float be = ot ? be1 : be0;                                    \
        _Pragma("unroll")                                                   \
        for (int rp = 0; rp < 2; ++rp) {                                    \
          float h0 = (YAC[mt][ot][rp * 2] - mu[rp * 2]) * rs[rp * 2] * ga + be; \
          h0 = h0 * __builtin_amdgcn_rcpf(1.0f + __expf(-h0));              \
          float h1 = (YAC[mt][ot][rp * 2 + 1] - mu[rp * 2 + 1]) * rs[rp * 2 + 1] * ga + be; \
          h1 = h1 * __builtin_amdgcn_rcpf(1.0f + __expf(-h1));              \
          const int t2 = tt * 16 + mt * 8 + g * 2 + rp;                     \
          HRX[t2 * HROW + o] = pk2(h0, h1);                                 \
        }                                                                   \
      }                                                                     \
    }                                                                       \
  } while (0)

  // out-GEMM from HRX -> global at chunk KC
#define OUTGEMM(HRX, KC) do {                                               \
    f32x4 oac0 = {}, oac1 = {};                                             \
    _Pragma("unroll")                                                       \
    for (int kt = 0; kt < 8; ++kt) {                                        \
      bf16x8 Aa0, Aa1;                                                      \
      {                                                                     \
        union { bf16x8 v; u32x4 u; } Ax;                                    \
        Ax.u = *(const u32x4*)&HRX[(l15) * HROW + kt * 16 + g * 4];         \
        Aa0 = Ax.v;                                                         \
        Ax.u = *(const u32x4*)&HRX[(16 + l15) * HROW + kt * 16 + g * 4];    \
        Aa1 = Ax.v;                                                         \
      }                                                                     \
      oac0 = __builtin_amdgcn_mfma_f32_16x16x32_bf16(Aa0, wf[kt], oac0, 0, 0, 0); \
      oac1 = __builtin_amdgcn_mfma_f32_16x16x32_bf16(Aa1, wf[kt], oac1, 0, 0, 0); \
    }                                                                       \
    const int o = w * 16 + l15;                                             \
    float4 q0;                                                              \
    q0.x = oac0[0] + bia; q0.y = oac0[1] + bia;                             \
    q0.z = oac0[2] + bia; q0.w = oac0[3] + bia;                             \
    *(float4*)(out + ((size_t)(b * OCH + o)) * THALF + (KC) * 32 + g * 4) = q0; \
    float4 q1;                                                              \
    q1.x = oac1[0] + bia; q1.y = oac1[1] + bia;                             \
    q1.z = oac1[2] + bia; q1.w = oac1[3] + bia;                             \
    *(float4*)(out + ((size_t)(b * OCH + o)) * THALF + (KC) * 32 + 16 + g * 4) = q1; \
  } while (0)

  // ---- prologue: pair 0 -> V2a/V2b; prefetch pair 1 into registers ----
  LOAD_ST(kc0 + 0, sa0, sa1, sa2, sa3, sda);
  CORRECT_STORE(V2a, sa0, sa1, sa2, sa3, sda);
  LOAD_ST(kc0 + 1, sb0, sb1, sb2, sb3, sdb);
  CORRECT_STORE(V2b, sb0, sb1, sb2, sb3, sdb);
  LOAD_ST(kc0 + 2, sa0, sa1, sa2, sa3, sda);
  LOAD_ST(kc0 + 3, sb0, sb1, sb2, sb3, sdb);
  rawbar();

  #pragma unroll 1
  for (int i = 0; i < NCHK / 2; ++i) {
    const int kcA = kc0 + 2 * i;
    const int kcB = kcA + 1;

    // ---- B: two independent y-GEMMs + LN partials ----
    f32x4 yacA[2][2] = {};
    f32x4 yacB[2][2] = {};
    YGEMM(V2a, yacA, 0);
    YGEMM(V2b, yacB, 1);
    rawbar();   // C: Lex visible; V2a/V2b fully read

    // ---- D: LN/SiLU both chunks; stage next pair into V2; prefetch pair i+2 ----
    LNSILU(Hra, yacA, 0);
    LNSILU(Hrb, yacB, 1);
    if (i + 1 < NCHK / 2) {
      CORRECT_STORE(V2a, sa0, sa1, sa2, sa3, sda);
      CORRECT_STORE(V2b, sb0, sb1, sb2, sb3, sdb);
      if (i + 2 < NCHK / 2) {
        LOAD_ST(kcA + 4, sa0, sa1, sa2, sa3, sda);
        LOAD_ST(kcB + 4, sb0, sb1, sb2, sb3, sdb);
      }
    }
    rawbar();   // E: Hr + next-pair V2 visible

    // ---- F: two independent out-GEMMs -> direct stores ----
    OUTGEMM(Hra, kcA);
    OUTGEMM(Hrb, kcB);
  }
#undef LOAD_ST
#undef CORRECT_ROW
#undef CORRECT_STORE
#undef YGEMM
#undef LNSILU
#undef OUTGEMM
}

// ---------------- launch ----------------
extern "C" void kernel_launch(void* const* d_in, const int* in_sizes, int n_in,
                              void* d_out, int out_size, void* d_ws, size_t ws_size,
                              hipStream_t stream) {
  const float* x    = (const float*)d_in[0];
  const float* rl   = (const float*)d_in[1];
  const float* Bc   = (const float*)d_in[2];
  const float* Cm   = (const float*)d_in[3];
  const float* lng  = (const float*)d_in[4];
  const float* lnb  = (const float*)d_in[5];
  const float* W    = (const float*)d_in[6];
  const float* bias = (const float*)d_in[7];
  float* out = (float*)d_out;

  char* ws = (char*)d_ws;
  unsigned short* BdT = (unsigned short*)(ws);            // 64 KB
  unsigned short* CT  = (unsigned short*)(ws + 65536);    // 64 KB
  unsigned short* Wb  = (unsigned short*)(ws + 131072);   // 64 KB
  float* Ad    = (float*)(ws + 196608);                   // 1 KB
  float* rL    = (float*)(ws + 197632);                   // 1 KB
  float* PWf   = (float*)(ws + 198656);                   // 32 KB
  float* carry = (float*)(ws + 231424);                   // 2 MB
  unsigned int* S = (unsigned int*)(ws + 231424 + 2097152); // 64 MB

  k_prep<<<417, 256, 0, stream>>>(rl, Bc, Cm, W, BdT, CT, Wb, Ad, rL, PWf);
  k_scan<<<BATCH * (NCHUNK / SCHK), 512, 0, stream>>>(x, BdT, Ad, S, carry);
  k_combine<<<BATCH * 32, 256, 0, stream>>>(carry, rL);
  k_apply<<<BATCH * (NCHUNK / NCHK), 512, 0, stream>>>(S, CT, Wb, PWf, Ad, carry,
                                                       lng, lnb, bias, out);
}

// Round 19
// 91.579 us; speedup vs baseline: 1.2278x; 1.0040x over previous
//
#include <hip/hip_runtime.h>

#define BATCH 8
#define CIN 128
#define OCH 128
#define T_LEN 16384
#define NS 256
#define CHUNK 64
#define NCHUNK (T_LEN / CHUNK)   // 256
#define THALF (T_LEN / 2)        // 8192
#define SCHUNK 8192              // u32 per chunk image in global: 32 rows x 256 n
#define HROW 132                 // Hr row stride (u32)
#define NCHK 8                   // chunks per apply block (4 pairs) -> grid 256 = 1 block/CU
#define SCHK 4                   // chunks per scan block -> grid 512 = 2 blocks/CU

typedef __attribute__((ext_vector_type(8))) short bf16x8;
typedef __attribute__((ext_vector_type(4))) float f32x4;
typedef __attribute__((ext_vector_type(4))) unsigned int u32x4;

__device__ __forceinline__ unsigned int pk2(float lo, float hi) {
  unsigned int d;
  asm("v_cvt_pk_bf16_f32 %0, %1, %2" : "=v"(d) : "v"(lo), "v"(hi));
  return d;
}
__device__ __forceinline__ unsigned short f2bf(float f) {
  unsigned int u = __float_as_uint(f);
  u += 0x7fffu + ((u >> 16) & 1u);
  return (unsigned short)(u >> 16);
}
__device__ __forceinline__ float softplusf_(float v) {
  return (v > 20.0f) ? v : log1pf(expf(v));
}
// barrier that does NOT drain vmcnt (keeps global prefetch in flight)
__device__ __forceinline__ void rawbar() {
  __builtin_amdgcn_sched_barrier(0);
  asm volatile("s_waitcnt lgkmcnt(0)" ::: "memory");
  __builtin_amdgcn_sched_barrier(0);
  __builtin_amdgcn_s_barrier();
  __builtin_amdgcn_sched_barrier(0);
}

// ---------------- prep: weights -> bf16, A_d, A_d^L, PWf[tp][n] = A_n^(2tp+1) ----------------
__global__ __launch_bounds__(256) void k_prep(
    const float* __restrict__ rl, const float* __restrict__ Bc,
    const float* __restrict__ Cm, const float* __restrict__ W,
    unsigned short* __restrict__ BdT, unsigned short* __restrict__ CT,
    unsigned short* __restrict__ Wb, float* __restrict__ Ad, float* __restrict__ rL,
    float* __restrict__ PWf)
{
  const int tid = blockIdx.x * 256 + threadIdx.x;
  if (tid < NS * CIN) {                       // BdT[n][c] = B_c[c][n] * (A_d-1)/lam
    const int n = tid >> 7, c = tid & 127;
    float lam = -softplusf_(rl[n]);
    float ad = expf(lam);
    float sc = (ad - 1.0f) / lam;
    BdT[tid] = f2bf(Bc[c * NS + n] * sc);
  } else if (tid < 2 * NS * CIN) {            // CT[o][n] = C[n][o]
    const int i = tid - NS * CIN;
    const int o = i >> 8, n = i & 255;
    CT[i] = f2bf(Cm[n * OCH + o]);
  } else if (tid < 3 * NS * CIN) {            // Wb[o][c2] = W[o][c2]
    const int i = tid - 2 * NS * CIN;
    Wb[i] = f2bf(W[i]);
  } else if (tid < 3 * NS * CIN + NS) {
    const int n = tid - 3 * NS * CIN;
    float lam = -softplusf_(rl[n]);
    Ad[n] = expf(lam);
    rL[n] = expf(lam * (float)CHUNK);
  } else if (tid < 3 * NS * CIN + NS + 32 * NS) {   // PWf[tp][n] = A_n^(2tp+1)
    const int i = tid - (3 * NS * CIN + NS);
    const int tp = i >> 8, n = i & 255;
    float lam = -softplusf_(rl[n]);
    PWf[i] = expf(lam * (float)(2 * tp + 1));
  }
}

// ---------------- chunk-carry combine: Hillis-Steele, 256 blocks (8 n per block) ----------------
__global__ __launch_bounds__(256) void k_combine(float* __restrict__ carry,
                                                 const float* __restrict__ rL)
{
  const int b = blockIdx.x >> 5;
  const int ng = blockIdx.x & 31;     // n-group of 8
  const int t = threadIdx.x;          // chunk index
  __shared__ float Y[8][NCHUNK];
  float* base = carry + ((size_t)b * NCHUNK + t) * NS + ng * 8;
  #pragma unroll
  for (int i4 = 0; i4 < 2; ++i4) {
    float4 q = *(const float4*)(base + i4 * 4);
    Y[i4 * 4 + 0][t] = q.x; Y[i4 * 4 + 1][t] = q.y;
    Y[i4 * 4 + 2][t] = q.z; Y[i4 * 4 + 3][t] = q.w;
  }
  float rp[8];
  #pragma unroll
  for (int i = 0; i < 8; ++i) rp[i] = rL[ng * 8 + i];
  __syncthreads();
  for (int d = 1; d < NCHUNK; d <<= 1) {
    float tmp[8];
    #pragma unroll
    for (int i = 0; i < 8; ++i) tmp[i] = (t >= d) ? Y[i][t - d] : 0.0f;
    __syncthreads();
    #pragma unroll
    for (int i = 0; i < 8; ++i) { Y[i][t] += rp[i] * tmp[i]; rp[i] *= rp[i]; }
    __syncthreads();
  }
  const int tm = (t == 0) ? 0 : (t - 1);
  #pragma unroll
  for (int i4 = 0; i4 < 2; ++i4) {
    float a = Y[i4 * 4 + 0][tm], bb = Y[i4 * 4 + 1][tm];
    float c = Y[i4 * 4 + 2][tm], dd = Y[i4 * 4 + 3][tm];
    float4 q;
    q.x = (t == 0) ? 0.0f : a;  q.y = (t == 0) ? 0.0f : bb;
    q.z = (t == 0) ? 0.0f : c;  q.w = (t == 0) ? 0.0f : dd;
    *(float4*)(base + i4 * 4) = q;
  }
}

// ---------------- k_scan: persistent 4-chunk blocks, prefetch-pipelined (R18 exact) ----------------
__global__ __launch_bounds__(512, 3) void k_scan(
    const float* __restrict__ x,
    const unsigned short* __restrict__ BdT,
    const float* __restrict__ Ad,
    unsigned int* __restrict__ s0,
    float* __restrict__ carry)
{
  const int bid = blockIdx.x;
  const int b = bid / (NCHUNK / SCHK);
  const int kc0 = (bid % (NCHUNK / SCHK)) * SCHK;
  const int tid = threadIdx.x;
  const int w = tid >> 6, l = tid & 63, l15 = l & 15, g = l >> 4;

  __shared__ __align__(16) unsigned int Xt[2][64 * 64];  // 2 x 16 KB, swizzled bf16 pairs

  bf16x8 Bf[2][4];
  #pragma unroll
  for (int nt = 0; nt < 2; ++nt)
    #pragma unroll
    for (int kt = 0; kt < 4; ++kt)
      Bf[nt][kt] = *(const bf16x8*)&BdT[(w * 32 + nt * 16 + l15) * CIN + kt * 32 + g * 8];

  float A1[2], A2[2], A3[2], A4[2], A8[2], A16[2], A4G[2], M1[2], M2[2];
  #pragma unroll
  for (int nt = 0; nt < 2; ++nt) {
    const float a1 = Ad[w * 32 + nt * 16 + l15];
    A1[nt] = a1; A2[nt] = a1 * a1; A3[nt] = A2[nt] * a1; A4[nt] = A2[nt] * A2[nt];
    A8[nt] = A4[nt] * A4[nt]; A16[nt] = A8[nt] * A8[nt];
    float a4g = 1.0f;
    if (g & 1) a4g *= A4[nt];
    if (g & 2) a4g *= A8[nt];
    A4G[nt] = a4g;
    M1[nt] = (g >= 1) ? A4[nt] : 0.0f;
    M2[nt] = (g >= 2) ? A8[nt] : 0.0f;
  }

  const int c2 = w * 8 + (l & 7);
  const int t0b = (l >> 3) * 8;
  const float* xbase = x + ((size_t)(b * CIN + 2 * c2)) * T_LEN + t0b;

  f32x4 xa0, xa1, xb0, xb1;
  {
    const float* r0 = xbase + kc0 * CHUNK;
    xa0 = *(const f32x4*)r0;
    xa1 = *(const f32x4*)(r0 + 4);
    xb0 = *(const f32x4*)(r0 + T_LEN);
    xb1 = *(const f32x4*)(r0 + T_LEN + 4);
  }

  int cur = 0;
  #pragma unroll 1
  for (int i = 0; i < SCHK; ++i) {
    const int kc = kc0 + i;

    #pragma unroll
    for (int k = 0; k < 8; ++k) {
      const int t = t0b + k;
      const float va = (k < 4) ? xa0[k & 3] : xa1[k & 3];
      const float vb = (k < 4) ? xb0[k & 3] : xb1[k & 3];
      Xt[cur][t * 64 + (c2 ^ ((t & 7) << 2))] = pk2(va, vb);
    }
    rawbar();

    if (i + 1 < SCHK) {
      const float* r0 = xbase + (kc + 1) * CHUNK;
      xa0 = *(const f32x4*)r0;
      xa1 = *(const f32x4*)(r0 + 4);
      xb0 = *(const f32x4*)(r0 + T_LEN);
      xb1 = *(const f32x4*)(r0 + T_LEN + 4);
    }

    f32x4 vac[4][2] = {};
    #pragma unroll
    for (int kt = 0; kt < 4; ++kt) {
      bf16x8 afr[4];
      #pragma unroll
      for (int mt = 0; mt < 4; ++mt)
        afr[mt] = *(const bf16x8*)&Xt[cur][(mt * 16 + l15) * 64 + ((kt * 16 + g * 4) ^ ((l15 & 7) << 2))];
      #pragma unroll
      for (int nt = 0; nt < 2; ++nt)
        #pragma unroll
        for (int mt = 0; mt < 4; ++mt)
          vac[mt][nt] = __builtin_amdgcn_mfma_f32_16x16x32_bf16(afr[mt], Bf[nt][kt], vac[mt][nt], 0, 0, 0);
    }

    float crv[2];
    #pragma unroll
    for (int nt = 0; nt < 2; ++nt) {
      float cr = 0.0f;
      #pragma unroll
      for (int mt = 0; mt < 4; ++mt) {
        const float p0 = vac[mt][nt][0];
        const float p1 = fmaf(A1[nt], p0, vac[mt][nt][1]);
        const float p2 = fmaf(A1[nt], p1, vac[mt][nt][2]);
        const float p3 = fmaf(A1[nt], p2, vac[mt][nt][3]);
        float c0 = p3;
        float u = __shfl_up(c0, 16);
        c0 = fmaf(M1[nt], u, c0);
        u = __shfl_up(c0, 32);
        c0 = fmaf(M2[nt], u, c0);
        float e = __shfl_up(c0, 16);
        e = (g == 0) ? 0.0f : e;
        const float seed = fmaf(A4G[nt], cr, e);
        vac[mt][nt][0] = fmaf(A1[nt], seed, p0);
        vac[mt][nt][1] = fmaf(A2[nt], seed, p1);
        vac[mt][nt][2] = fmaf(A3[nt], seed, p2);
        vac[mt][nt][3] = fmaf(A4[nt], seed, p3);
        const float ctop = __shfl(c0, 48 + l15);
        cr = fmaf(A16[nt], cr, ctop);
      }
      crv[nt] = cr;
    }

    unsigned int* sc = s0 + (size_t)(b * NCHUNK + kc) * SCHUNK;
    #pragma unroll
    for (int mt = 0; mt < 4; ++mt)
      #pragma unroll
      for (int nt = 0; nt < 2; ++nt) {
        const int n = w * 32 + nt * 16 + l15;
        #pragma unroll
        for (int rp = 0; rp < 2; ++rp) {
          const int tp = mt * 8 + g * 2 + rp;
          sc[tp * 256 + n] = pk2(vac[mt][nt][rp * 2], vac[mt][nt][rp * 2 + 1]);
        }
      }
    if (g == 0) {
      #pragma unroll
      for (int nt = 0; nt < 2; ++nt)
        carry[((size_t)b * NCHUNK + kc) * NS + (w * 32 + nt * 16 + l15)] = crv[nt];
    }
    cur ^= 1;
  }
}

// ---------------- k_apply: PAIRED chunks, F rotated into next B interval ----------------
// R19: previously F(i) ended its interval alone; rotating it to sit adjacent to B(i+1)
// (same barrier interval, independent LDS buffers + accumulators) lets the scheduler
// interleave two MFMA/LDS streams where the lockstep convoy stalls. Hazards unchanged:
// F(i-1) reads Hr written D(i-1) [after barE(i-1)]; D(i) overwrites Hr only after barC(i).
__global__ __launch_bounds__(512, 2) void k_apply(
    const unsigned int* __restrict__ S,
    const unsigned short* __restrict__ CT,
    const unsigned short* __restrict__ Wb,
    const float* __restrict__ PWf,
    const float* __restrict__ Ad,
    const float* __restrict__ carry,
    const float* __restrict__ lng, const float* __restrict__ lnb,
    const float* __restrict__ bias,
    float* __restrict__ out)
{
  const int bid = blockIdx.x;
  const int b = bid / (NCHUNK / NCHK);
  const int kc0 = (bid % (NCHUNK / NCHK)) * NCHK;
  const int tid = threadIdx.x;
  const int w = tid >> 6, l = tid & 63, l15 = l & 15, g = l >> 4;
  const int tt = w >> 2, oq = w & 3;

  __shared__ __align__(16) unsigned short V2a[64 * 256];  // 32 KB, swizzled bf16 [t][n]
  __shared__ __align__(16) unsigned short V2b[64 * 256];  // 32 KB
  __shared__ __align__(16) unsigned int Hra[32 * HROW];   // 16.9 KB
  __shared__ __align__(16) unsigned int Hrb[32 * HROW];   // 16.9 KB
  __shared__ __align__(16) float Lexf[2][64 * 8];         // 4 KB

  const f32x4 adv = *(const f32x4*)&Ad[4 * l];

  bf16x8 ctf[8][2];
  #pragma unroll
  for (int kt = 0; kt < 8; ++kt)
    #pragma unroll
    for (int ot = 0; ot < 2; ++ot)
      ctf[kt][ot] = *(const bf16x8*)&CT[(oq * 32 + ot * 16 + l15) * NS + kt * 32 + g * 8];
  bf16x8 wf[8];
  #pragma unroll
  for (int kt = 0; kt < 8; ++kt)
    wf[kt] = *(const bf16x8*)&Wb[(w * 16 + l15) * NS + kt * 32 + g * 8];
  f32x4 pwv[4];
  #pragma unroll
  for (int r = 0; r < 4; ++r)
    pwv[r] = *(const f32x4*)&PWf[(r * 8 + w) * 256 + 4 * l];
  const float ga0 = lng[oq * 32 + l15],      be0 = lnb[oq * 32 + l15];
  const float ga1 = lng[oq * 32 + 16 + l15], be1 = lnb[oq * 32 + 16 + l15];
  const float bia = bias[w * 16 + l15];

  u32x4 sa0, sa1, sa2, sa3, sb0, sb1, sb2, sb3;
  f32x4 sda, sdb;

#define LOAD_ST(KC, T0, T1, T2, T3, SD) do {                                \
    const unsigned int* scb_ = S + (size_t)(b * NCHUNK + (KC)) * SCHUNK;    \
    T0 = *(const u32x4*)&scb_[0 * 2048 + tid * 4];                          \
    T1 = *(const u32x4*)&scb_[1 * 2048 + tid * 4];                          \
    T2 = *(const u32x4*)&scb_[2 * 2048 + tid * 4];                          \
    T3 = *(const u32x4*)&scb_[3 * 2048 + tid * 4];                          \
    SD = *(const f32x4*)&carry[((size_t)b * NCHUNK + (KC)) * NS + 4 * l];   \
  } while (0)

#define CORRECT_ROW(DSTV, QV, RR, SD) do {                                  \
    const float e00 = SD[0] * pwv[RR][0];                                   \
    const float e01 = SD[1] * pwv[RR][1];                                   \
    const float e02 = SD[2] * pwv[RR][2];                                   \
    const float e03 = SD[3] * pwv[RR][3];                                   \
    const float lo0 = __uint_as_float(QV[0] << 16) + e00;                   \
    const float hi0 = __uint_as_float(QV[0] & 0xffff0000u) + e00 * adv[0];  \
    const float lo1 = __uint_as_float(QV[1] << 16) + e01;                   \
    const float hi1 = __uint_as_float(QV[1] & 0xffff0000u) + e01 * adv[1];  \
    const float lo2 = __uint_as_float(QV[2] << 16) + e02;                   \
    const float hi2 = __uint_as_float(QV[2] & 0xffff0000u) + e02 * adv[2];  \
    const float lo3 = __uint_as_float(QV[3] << 16) + e03;                   \
    const float hi3 = __uint_as_float(QV[3] & 0xffff0000u) + e03 * adv[3];  \
    const int t0_ = ((RR) * 8 + w) * 2;                                     \
    const int t1_ = t0_ + 1;                                                \
    uint2 wlo; wlo.x = pk2(lo0, lo1); wlo.y = pk2(lo2, lo3);                \
    uint2 whi; whi.x = pk2(hi0, hi1); whi.y = pk2(hi2, hi3);                \
    *(uint2*)&DSTV[t0_ * 256 + ((((l >> 1) ^ ((t0_ & 7) << 2)) << 3) | ((l & 1) << 2))] = wlo; \
    *(uint2*)&DSTV[t1_ * 256 + ((((l >> 1) ^ ((t1_ & 7) << 2)) << 3) | ((l & 1) << 2))] = whi; \
  } while (0)

#define CORRECT_STORE(DSTV, T0, T1, T2, T3, SD) do {                        \
    CORRECT_ROW(DSTV, T0, 0, SD);                                           \
    CORRECT_ROW(DSTV, T1, 1, SD);                                           \
    CORRECT_ROW(DSTV, T2, 2, SD);                                           \
    CORRECT_ROW(DSTV, T3, 3, SD);                                           \
  } while (0)

#define YGEMM(V2X, YAC, IDX) do {                                           \
    _Pragma("unroll")                                                       \
    for (int kt = 0; kt < 8; ++kt) {                                        \
      bf16x8 As0, As1;                                                      \
      {                                                                     \
        const int t0 = tt * 32 + l15;                                       \
        As0 = *(const bf16x8*)&V2X[t0 * 256 + (((kt * 4 + g) ^ ((t0 & 7) << 2)) << 3)]; \
        const int t1 = tt * 32 + 16 + l15;                                  \
        As1 = *(const bf16x8*)&V2X[t1 * 256 + (((kt * 4 + g) ^ ((t1 & 7) << 2)) << 3)]; \
      }                                                                     \
      _Pragma("unroll")                                                     \
      for (int ot = 0; ot < 2; ++ot) {                                      \
        YAC[0][ot] = __builtin_amdgcn_mfma_f32_16x16x32_bf16(As0, ctf[kt][ot], YAC[0][ot], 0, 0, 0); \
        YAC[1][ot] = __builtin_amdgcn_mfma_f32_16x16x32_bf16(As1, ctf[kt][ot], YAC[1][ot], 0, 0, 0); \
      }                                                                     \
    }                                                                       \
    _Pragma("unroll")                                                       \
    for (int mt = 0; mt < 2; ++mt)                                          \
      _Pragma("unroll")                                                     \
      for (int r = 0; r < 4; ++r) {                                         \
        float s1 = YAC[mt][0][r] + YAC[mt][1][r];                           \
        float s2 = YAC[mt][0][r] * YAC[mt][0][r] + YAC[mt][1][r] * YAC[mt][1][r]; \
        _Pragma("unroll")                                                   \
        for (int d = 1; d < 16; d <<= 1) { s1 += __shfl_xor(s1, d); s2 += __shfl_xor(s2, d); } \
        if (l15 == 0) {                                                     \
          const int t = tt * 32 + mt * 16 + g * 4 + r;                      \
          *(float2*)&Lexf[IDX][t * 8 + oq * 2] = make_float2(s1, s2);       \
        }                                                                   \
      }                                                                     \
  } while (0)

#define LNSILU(HRX, YAC, IDX) do {                                          \
    _Pragma("unroll")                                                       \
    for (int mt = 0; mt < 2; ++mt) {                                        \
      float mu[4], rs[4];                                                   \
      _Pragma("unroll")                                                     \
      for (int r = 0; r < 4; ++r) {                                         \
        const int t = tt * 32 + mt * 16 + g * 4 + r;                        \
        const float4 f0 = *(const float4*)&Lexf[IDX][t * 8];                \
        const float4 f1 = *(const float4*)&Lexf[IDX][t * 8 + 4];            \
        const float m = (f0.x + f0.z + f1.x + f1.z) * (1.0f / 128.0f);      \
        const float va = (f0.y + f0.w + f1.y + f1.w) * (1.0f / 128.0f) - m * m; \
        mu[r] = m;                                                          \
        rs[r] = rsqrtf(va + 1e-5f);                                         \
      }                                                                     \
      _Pragma("unroll")                                                     \
      for (int ot = 0; ot < 2; ++ot) {                                      \
        const int o = oq * 32 + ot * 16 + l15;                              \
        const float ga = ot ? ga1 : ga0;                                    \
        const float be = ot ? be1 : be0;                                    \
        _Pragma("unroll")                                                   \
        for (int rp = 0; rp < 2; ++rp) {                                    \
          float h0 = (YAC[mt][ot][rp * 2] - mu[rp * 2]) * rs[rp * 2] * ga + be; \
          h0 = h0 * __builtin_amdgcn_rcpf(1.0f + __expf(-h0));              \
          float h1 = (YAC[mt][ot][rp * 2 + 1] - mu[rp * 2 + 1]) * rs[rp * 2 + 1] * ga + be; \
          h1 = h1 * __builtin_amdgcn_rcpf(1.0f + __expf(-h1));              \
          const int t2 = tt * 16 + mt * 8 + g * 2 + rp;                     \
          HRX[t2 * HROW + o] = pk2(h0, h1);                                 \
        }                                                                   \
      }                                                                     \
    }                                                                       \
  } while (0)

#define OUTGEMM(HRX, KC) do {                                               \
    f32x4 oac0 = {}, oac1 = {};                                             \
    _Pragma("unroll")                                                       \
    for (int kt = 0; kt < 8; ++kt) {                                        \
      bf16x8 Aa0, Aa1;                                                      \
      {                                                                     \
        union { bf16x8 v; u32x4 u; } Ax;                                    \
        Ax.u = *(const u32x4*)&HRX[(l15) * HROW + kt * 16 + g * 4];         \
        Aa0 = Ax.v;                                                         \
        Ax.u = *(const u32x4*)&HRX[(16 + l15) * HROW + kt * 16 + g * 4];    \
        Aa1 = Ax.v;                                                         \
      }                                                                     \
      oac0 = __builtin_amdgcn_mfma_f32_16x16x32_bf16(Aa0, wf[kt], oac0, 0, 0, 0); \
      oac1 = __builtin_amdgcn_mfma_f32_16x16x32_bf16(Aa1, wf[kt], oac1, 0, 0, 0); \
    }                                                                       \
    const int o = w * 16 + l15;                                             \
    float4 q0;                                                              \
    q0.x = oac0[0] + bia; q0.y = oac0[1] + bia;                             \
    q0.z = oac0[2] + bia; q0.w = oac0[3] + bia;                             \
    *(float4*)(out + ((size_t)(b * OCH + o)) * THALF + (KC) * 32 + g * 4) = q0; \
    float4 q1;                                                              \
    q1.x = oac1[0] + bia; q1.y = oac1[1] + bia;                             \
    q1.z = oac1[2] + bia; q1.w = oac1[3] + bia;                             \
    *(float4*)(out + ((size_t)(b * OCH + o)) * THALF + (KC) * 32 + 16 + g * 4) = q1; \
  } while (0)

  // ---- prologue: pair 0 -> V2a/V2b; prefetch pair 1 into registers ----
  LOAD_ST(kc0 + 0, sa0, sa1, sa2, sa3, sda);
  CORRECT_STORE(V2a, sa0, sa1, sa2, sa3, sda);
  LOAD_ST(kc0 + 1, sb0, sb1, sb2, sb3, sdb);
  CORRECT_STORE(V2b, sb0, sb1, sb2, sb3, sdb);
  LOAD_ST(kc0 + 2, sa0, sa1, sa2, sa3, sda);
  LOAD_ST(kc0 + 3, sb0, sb1, sb2, sb3, sdb);
  rawbar();

  #pragma unroll 1
  for (int i = 0; i < NCHK / 2; ++i) {
    const int kcA = kc0 + 2 * i;
    const int kcB = kcA + 1;

    // ---- B interval: F(i-1) rotated in, adjacent to B(i): independent MFMA+LDS streams ----
    f32x4 yacA[2][2] = {};
    f32x4 yacB[2][2] = {};
    if (i > 0) {
      OUTGEMM(Hra, kcA - 2);
      OUTGEMM(Hrb, kcB - 2);
    }
    YGEMM(V2a, yacA, 0);
    YGEMM(V2b, yacB, 1);
    rawbar();   // C: Lex visible; V2a/V2b fully read; Hr(i-1) fully read

    // ---- D: LN/SiLU both chunks -> Hr(i); stage next pair into V2; prefetch pair i+2 ----
    LNSILU(Hra, yacA, 0);
    LNSILU(Hrb, yacB, 1);
    if (i + 1 < NCHK / 2) {
      CORRECT_STORE(V2a, sa0, sa1, sa2, sa3, sda);
      CORRECT_STORE(V2b, sb0, sb1, sb2, sb3, sdb);
      if (i + 2 < NCHK / 2) {
        LOAD_ST(kcA + 4, sa0, sa1, sa2, sa3, sda);
        LOAD_ST(kcB + 4, sb0, sb1, sb2, sb3, sdb);
      }
    }
    rawbar();   // E: Hr(i) + next-pair V2 visible
  }

  // ---- epilogue: out-GEMMs for the final pair ----
  OUTGEMM(Hra, kc0 + NCHK - 2);
  OUTGEMM(Hrb, kc0 + NCHK - 1);
#undef LOAD_ST
#undef CORRECT_ROW
#undef CORRECT_STORE
#undef YGEMM
#undef LNSILU
#undef OUTGEMM
}

// ---------------- launch ----------------
extern "C" void kernel_launch(void* const* d_in, const int* in_sizes, int n_in,
                              void* d_out, int out_size, void* d_ws, size_t ws_size,
                              hipStream_t stream) {
  const float* x    = (const float*)d_in[0];
  const float* rl   = (const float*)d_in[1];
  const float* Bc   = (const float*)d_in[2];
  const float* Cm   = (const float*)d_in[3];
  const float* lng  = (const float*)d_in[4];
  const float* lnb  = (const float*)d_in[5];
  const float* W    = (const float*)d_in[6];
  const float* bias = (const float*)d_in[7];
  float* out = (float*)d_out;

  char* ws = (char*)d_ws;
  unsigned short* BdT = (unsigned short*)(ws);            // 64 KB
  unsigned short* CT  = (unsigned short*)(ws + 65536);    // 64 KB
  unsigned short* Wb  = (unsigned short*)(ws + 131072);   // 64 KB
  float* Ad    = (float*)(ws + 196608);                   // 1 KB
  float* rL    = (float*)(ws + 197632);                   // 1 KB
  float* PWf   = (float*)(ws + 198656);                   // 32 KB
  float* carry = (float*)(ws + 231424);                   // 2 MB
  unsigned int* S = (unsigned int*)(ws + 231424 + 2097152); // 64 MB

  k_prep<<<417, 256, 0, stream>>>(rl, Bc, Cm, W, BdT, CT, Wb, Ad, rL, PWf);
  k_scan<<<BATCH * (NCHUNK / SCHK), 512, 0, stream>>>(x, BdT, Ad, S, carry);
  k_combine<<<BATCH * 32, 256, 0, stream>>>(carry, rL);
  k_apply<<<BATCH * (NCHUNK / NCHK), 512, 0, stream>>>(S, CT, Wb, PWf, Ad, carry,
                                                       lng, lnb, bias, out);
}